// Round 1
// baseline (172.377 us; speedup 1.0000x reference)
//
#include <hip/hip_runtime.h>
#include <hip/hip_bf16.h>

typedef __bf16 bf16;
typedef __attribute__((ext_vector_type(8))) __bf16 bf16x8;
typedef __attribute__((ext_vector_type(4))) __bf16 bf16x4;
typedef __attribute__((ext_vector_type(4))) float f32x4;

__device__ __forceinline__ void gload_lds16(const void* g, void* l) {
  __builtin_amdgcn_global_load_lds((const __attribute__((address_space(1))) void*)g,
                                   (__attribute__((address_space(3))) void*)l, 16, 0, 0);
}

// ---------------- f32 -> bf16 elementwise convert ----------------
__global__ __launch_bounds__(256) void cvt_kernel(const float4* __restrict__ in,
                                                  bf16x4* __restrict__ out, int n4) {
  int i = blockIdx.x * 256 + threadIdx.x;
  if (i < n4) {
    float4 v = in[i];
    bf16x4 o;
    o[0] = (bf16)v.x; o[1] = (bf16)v.y; o[2] = (bf16)v.z; o[3] = (bf16)v.w;
    out[i] = o;
  }
}

// ---------------- transpose+convert 1024x1024 weights: T[n][k] = bf16(W[k][n]) ----------------
__global__ __launch_bounds__(256) void wtrans_kernel(
    const float* __restrict__ W0, const float* __restrict__ W1,
    const float* __restrict__ W2, const float* __restrict__ W3,
    bf16* __restrict__ T0, bf16* __restrict__ T1,
    bf16* __restrict__ T2, bf16* __restrict__ T3) {
  const float* W; bf16* T;
  switch (blockIdx.z) {
    case 0: W = W0; T = T0; break;
    case 1: W = W1; T = T1; break;
    case 2: W = W2; T = T2; break;
    default: W = W3; T = T3; break;
  }
  __shared__ float t[32][33];
  int tx = threadIdx.x, ty = threadIdx.y;
  int bn = blockIdx.x * 32, bk = blockIdx.y * 32;
#pragma unroll
  for (int i = 0; i < 32; i += 8)
    t[ty + i][tx] = W[(size_t)(bk + ty + i) * 1024 + bn + tx];
  __syncthreads();
#pragma unroll
  for (int i = 0; i < 32; i += 8)
    T[(size_t)(bn + ty + i) * 1024 + bk + tx] = (bf16)t[tx][ty + i];
}

// ---------------- GEMM: C[4096][1024] = A[4096][1024] x Bt[1024(n)][1024(k)]^T + bias ----------------
// MODE 0: bf16 row-major out.  MODE 1: f32 relu out.  MODE 2: bf16 transposed out ([B][1024ch][2048n]).
template <int MODE>
__global__ __launch_bounds__(256) void gemm_bt(
    const bf16* __restrict__ A, const bf16* __restrict__ Bt,
    const float* __restrict__ bias, void* __restrict__ Cout) {
  constexpr int K = 1024;
  __shared__ bf16 As[128 * 32];
  __shared__ bf16 Bs[128 * 32];
  const int tid = threadIdx.x;
  const int wave = tid >> 6, lane = tid & 63;
  const int g = lane >> 4, r15 = lane & 15;
  const int m0 = blockIdx.x * 128, n0 = blockIdx.y * 128;
  const int wr = wave >> 1, wc = wave & 1;

  f32x4 acc[4][4] = {};

  const int c0 = tid, c1 = tid + 256;
  const int row0 = c0 >> 2, ch0 = c0 & 3;
  const int row1 = c1 >> 2, ch1 = c1 & 3;

  for (int k0 = 0; k0 < K; k0 += 32) {
    __syncthreads();
    gload_lds16(A + (size_t)(m0 + row0) * K + k0 + ch0 * 8, (char*)As + c0 * 16);
    gload_lds16(Bt + (size_t)(n0 + row0) * K + k0 + ch0 * 8, (char*)Bs + c0 * 16);
    gload_lds16(A + (size_t)(m0 + row1) * K + k0 + ch1 * 8, (char*)As + c1 * 16);
    gload_lds16(Bt + (size_t)(n0 + row1) * K + k0 + ch1 * 8, (char*)Bs + c1 * 16);
    __syncthreads();

    bf16x8 af[4], bfr[4];
#pragma unroll
    for (int mi = 0; mi < 4; ++mi)
      af[mi] = *(const bf16x8*)((const char*)As + ((wr * 64 + mi * 16 + r15) * 64 + g * 16));
#pragma unroll
    for (int nj = 0; nj < 4; ++nj)
      bfr[nj] = *(const bf16x8*)((const char*)Bs + ((wc * 64 + nj * 16 + r15) * 64 + g * 16));
#pragma unroll
    for (int mi = 0; mi < 4; ++mi)
#pragma unroll
      for (int nj = 0; nj < 4; ++nj)
        acc[mi][nj] = __builtin_amdgcn_mfma_f32_16x16x32_bf16(af[mi], bfr[nj], acc[mi][nj], 0, 0, 0);
  }

#pragma unroll
  for (int mi = 0; mi < 4; ++mi) {
#pragma unroll
    for (int nj = 0; nj < 4; ++nj) {
      int row = m0 + wr * 64 + mi * 16 + g * 4;
      int col = n0 + wc * 64 + nj * 16 + r15;
      float bv = bias[col];
      if constexpr (MODE == 0) {
        bf16* C = (bf16*)Cout;
#pragma unroll
        for (int r = 0; r < 4; ++r)
          C[(size_t)(row + r) * 1024 + col] = (bf16)(acc[mi][nj][r] + bv);
      } else if constexpr (MODE == 1) {
        float* C = (float*)Cout;
#pragma unroll
        for (int r = 0; r < 4; ++r)
          C[(size_t)(row + r) * 1024 + col] = fmaxf(acc[mi][nj][r] + bv, 0.0f);
      } else {
        bf16* C = (bf16*)Cout;  // V^T: [B][1024][2048]
        int b = row >> 11, n = row & 2047;
        bf16x4 pk;
#pragma unroll
        for (int r = 0; r < 4; ++r)
          pk[r] = (bf16)(acc[mi][nj][r] + bv);
        *(bf16x4*)(C + ((size_t)b * 1024 + col) * 2048 + n) = pk;
      }
    }
  }
}

// ---------------- flash attention (no-max softmax; scores are tiny by construction) ----------------
// Q,K: [B][2048][1024] bf16 (head-sliced). V^T: [B][1024][2048] bf16. Oa: [B][2048][1024] bf16.
__global__ __launch_bounds__(256) void attn_kernel(
    const bf16* __restrict__ Q, const bf16* __restrict__ Kin,
    const bf16* __restrict__ Vt, bf16* __restrict__ Oa) {
  __shared__ bf16 Ks[64 * 64];
  __shared__ bf16 Vs[64 * 64];
  __shared__ bf16 Ps[4][32 * 72];
  const int tid = threadIdx.x;
  const int wave = tid >> 6, lane = tid & 63;
  const int g = lane >> 4, r15 = lane & 15;
  const int qt = blockIdx.x, bh = blockIdx.y;
  const int b = bh >> 4, h = bh & 15;
  const bf16* Qg = Q + ((size_t)b * 2048 + qt * 128) * 1024 + h * 64;
  const bf16* Kg = Kin + (size_t)b * 2048 * 1024 + h * 64;
  const bf16* Vg = Vt + ((size_t)b * 1024 + h * 64) * 2048;

  // Q fragments hoisted to registers for the whole KV loop
  bf16x8 qf_[2][2];
#pragma unroll
  for (int qf = 0; qf < 2; ++qf)
#pragma unroll
    for (int kb = 0; kb < 2; ++kb)
      qf_[qf][kb] = *(const bf16x8*)(Qg + (size_t)(wave * 32 + qf * 16 + r15) * 1024 + kb * 32 + g * 8);

  f32x4 o[2][4] = {};
  float ls[2][4] = {};
  const float scale = 0.022097086912079612f;  // 1/sqrt(2048)

  const int c0 = tid, c1 = tid + 256;
  const int srow0 = c0 >> 3, sch0 = (c0 & 7) ^ (srow0 & 7);  // XOR-swizzled source chunk
  const int srow1 = c1 >> 3, sch1 = (c1 & 7) ^ (srow1 & 7);

  for (int kv0 = 0; kv0 < 2048; kv0 += 64) {
    __syncthreads();
    gload_lds16(Kg + (size_t)(kv0 + srow0) * 1024 + sch0 * 8, (char*)Ks + c0 * 16);
    gload_lds16(Vg + (size_t)srow0 * 2048 + kv0 + sch0 * 8, (char*)Vs + c0 * 16);
    gload_lds16(Kg + (size_t)(kv0 + srow1) * 1024 + sch1 * 8, (char*)Ks + c1 * 16);
    gload_lds16(Vg + (size_t)srow1 * 2048 + kv0 + sch1 * 8, (char*)Vs + c1 * 16);
    __syncthreads();

    // S = Q K^T : per wave 32 q-rows x 64 kv
    f32x4 s[2][4] = {};
    bf16x8 kf[4][2];
#pragma unroll
    for (int kvf = 0; kvf < 4; ++kvf) {
      int row = kvf * 16 + r15;
#pragma unroll
      for (int kb = 0; kb < 2; ++kb) {
        int ch = (kb * 4 + g) ^ (row & 7);
        kf[kvf][kb] = *(const bf16x8*)((const char*)Ks + row * 128 + ch * 16);
      }
    }
#pragma unroll
    for (int qf = 0; qf < 2; ++qf)
#pragma unroll
      for (int kvf = 0; kvf < 4; ++kvf)
#pragma unroll
        for (int kb = 0; kb < 2; ++kb)
          s[qf][kvf] = __builtin_amdgcn_mfma_f32_16x16x32_bf16(qf_[qf][kb], kf[kvf][kb], s[qf][kvf], 0, 0, 0);

    // P = exp(s*scale); wave-private LDS relayout (C-frag -> A-frag); f32 row-sum partials
    bf16* Pw = &Ps[wave][0];
#pragma unroll
    for (int qf = 0; qf < 2; ++qf)
#pragma unroll
      for (int kvf = 0; kvf < 4; ++kvf)
#pragma unroll
        for (int r = 0; r < 4; ++r) {
          float p = __expf(s[qf][kvf][r] * scale);
          ls[qf][r] += p;
          Pw[(qf * 16 + g * 4 + r) * 72 + kvf * 16 + r15] = (bf16)p;
        }

    bf16x8 pa[2][2], vb[4][2];
#pragma unroll
    for (int qf = 0; qf < 2; ++qf)
#pragma unroll
      for (int kb = 0; kb < 2; ++kb)
        pa[qf][kb] = *(const bf16x8*)((const char*)Pw + (qf * 16 + r15) * 144 + kb * 64 + g * 16);
#pragma unroll
    for (int dvf = 0; dvf < 4; ++dvf) {
      int row = dvf * 16 + r15;
#pragma unroll
      for (int kb = 0; kb < 2; ++kb) {
        int ch = (kb * 4 + g) ^ (row & 7);
        vb[dvf][kb] = *(const bf16x8*)((const char*)Vs + row * 128 + ch * 16);
      }
    }
#pragma unroll
    for (int qf = 0; qf < 2; ++qf)
#pragma unroll
      for (int dvf = 0; dvf < 4; ++dvf)
#pragma unroll
        for (int kb = 0; kb < 2; ++kb)
          o[qf][dvf] = __builtin_amdgcn_mfma_f32_16x16x32_bf16(pa[qf][kb], vb[dvf][kb], o[qf][dvf], 0, 0, 0);
  }

  // row sums: reduce across the 16 lanes sharing g (bits 0-3) -> lands in O's C-layout rows
#pragma unroll
  for (int qf = 0; qf < 2; ++qf)
#pragma unroll
    for (int r = 0; r < 4; ++r) {
      float v = ls[qf][r];
      v += __shfl_xor(v, 1);
      v += __shfl_xor(v, 2);
      v += __shfl_xor(v, 4);
      v += __shfl_xor(v, 8);
      ls[qf][r] = v;
    }

#pragma unroll
  for (int qf = 0; qf < 2; ++qf)
#pragma unroll
    for (int dvf = 0; dvf < 4; ++dvf)
#pragma unroll
      for (int r = 0; r < 4; ++r) {
        float val = o[qf][dvf][r] / ls[qf][r];
        size_t row = (size_t)b * 2048 + qt * 128 + wave * 32 + qf * 16 + g * 4 + r;
        Oa[row * 1024 + h * 64 + dvf * 16 + r15] = (bf16)val;
      }
}

extern "C" void kernel_launch(void* const* d_in, const int* in_sizes, int n_in,
                              void* d_out, int out_size, void* d_ws, size_t ws_size,
                              hipStream_t stream) {
  (void)in_sizes; (void)n_in; (void)out_size; (void)ws_size;
  const float* x  = (const float*)d_in[0];
  const float* y  = (const float*)d_in[1];
  const float* Wq = (const float*)d_in[2];
  const float* bq = (const float*)d_in[3];
  const float* Wk = (const float*)d_in[4];
  const float* bk = (const float*)d_in[5];
  const float* Wv = (const float*)d_in[6];
  const float* bv = (const float*)d_in[7];
  const float* Wo = (const float*)d_in[8];
  const float* bo = (const float*)d_in[9];

  char* ws = (char*)d_ws;
  bf16* xb  = (bf16*)(ws + 0);
  bf16* yb  = (bf16*)(ws + 8388608);
  bf16* Qb  = (bf16*)(ws + 16777216);
  bf16* Kb  = (bf16*)(ws + 25165824);
  bf16* Vtb = (bf16*)(ws + 33554432);
  bf16* Oab = (bf16*)(ws + 41943040);
  bf16* Wqt = (bf16*)(ws + 50331648);
  bf16* Wkt = (bf16*)(ws + 52428800);
  bf16* Wvt = (bf16*)(ws + 54525952);
  bf16* Wot = (bf16*)(ws + 56623104);

  const int n4 = 4096 * 1024 / 4;
  cvt_kernel<<<n4 / 256, 256, 0, stream>>>((const float4*)x, (bf16x4*)xb, n4);
  cvt_kernel<<<n4 / 256, 256, 0, stream>>>((const float4*)y, (bf16x4*)yb, n4);
  wtrans_kernel<<<dim3(32, 32, 4), dim3(32, 8), 0, stream>>>(Wq, Wk, Wv, Wo, Wqt, Wkt, Wvt, Wot);
  gemm_bt<0><<<dim3(32, 8), 256, 0, stream>>>(xb, Wqt, bq, Qb);
  gemm_bt<0><<<dim3(32, 8), 256, 0, stream>>>(yb, Wkt, bk, Kb);
  gemm_bt<2><<<dim3(32, 8), 256, 0, stream>>>(yb, Wvt, bv, Vtb);
  attn_kernel<<<dim3(16, 32), 256, 0, stream>>>(Qb, Kb, Vtb, Oab);
  gemm_bt<1><<<dim3(32, 8), 256, 0, stream>>>(Oab, Wot, bo, d_out);
}

// Round 2
// 142.921 us; speedup vs baseline: 1.2061x; 1.2061x over previous
//
#include <hip/hip_runtime.h>
#include <hip/hip_bf16.h>

typedef __bf16 bf16;
typedef __attribute__((ext_vector_type(8))) __bf16 bf16x8;
typedef __attribute__((ext_vector_type(4))) __bf16 bf16x4;
typedef __attribute__((ext_vector_type(4))) float f32x4;

__device__ __forceinline__ void gload_lds16(const void* g, void* l) {
  __builtin_amdgcn_global_load_lds((const __attribute__((address_space(1))) void*)g,
                                   (__attribute__((address_space(3))) void*)l, 16, 0, 0);
}

// ---------------- f32 -> bf16 convert, x and y in one launch ----------------
__global__ __launch_bounds__(256) void cvt2_kernel(const float4* __restrict__ a,
                                                   const float4* __restrict__ b,
                                                   bf16x4* __restrict__ oa,
                                                   bf16x4* __restrict__ ob, int n4) {
  int i = blockIdx.x * 256 + threadIdx.x;
  const float4* in = a; bf16x4* out = oa;
  if (i >= n4) { in = b; out = ob; i -= n4; }
  float4 v = in[i];
  bf16x4 o;
  o[0] = (bf16)v.x; o[1] = (bf16)v.y; o[2] = (bf16)v.z; o[3] = (bf16)v.w;
  out[i] = o;
}

// ---------------- transpose+convert 1024x1024 weights: T[n][k] = bf16(W[k][n]) ----------------
__global__ __launch_bounds__(256) void wtrans_kernel(
    const float* __restrict__ W0, const float* __restrict__ W1,
    const float* __restrict__ W2, const float* __restrict__ W3,
    bf16* __restrict__ T0, bf16* __restrict__ T1,
    bf16* __restrict__ T2, bf16* __restrict__ T3) {
  const float* W; bf16* T;
  switch (blockIdx.z) {
    case 0: W = W0; T = T0; break;
    case 1: W = W1; T = T1; break;
    case 2: W = W2; T = T2; break;
    default: W = W3; T = T3; break;
  }
  __shared__ float t[32][33];
  int tx = threadIdx.x, ty = threadIdx.y;
  int bn = blockIdx.x * 32, bk = blockIdx.y * 32;
#pragma unroll
  for (int i = 0; i < 32; i += 8)
    t[ty + i][tx] = W[(size_t)(bk + ty + i) * 1024 + bn + tx];
  __syncthreads();
#pragma unroll
  for (int i = 0; i < 32; i += 8)
    T[(size_t)(bn + ty + i) * 1024 + bk + tx] = (bf16)t[tx][ty + i];
}

// ---------------- merged Q/K/V projection GEMM, 128x128 tile, double-buffered ----------------
// z=0: Q = xb*Wqt+bq (row-major bf16); z=1: K = yb*Wkt+bk (row-major bf16);
// z=2: V = yb*Wvt+bv written transposed ([B][1024ch][2048n] bf16).
__global__ __launch_bounds__(256) void gemm_qkv(
    const bf16* __restrict__ xb, const bf16* __restrict__ yb,
    const bf16* __restrict__ Wqt, const bf16* __restrict__ Wkt, const bf16* __restrict__ Wvt,
    const float* __restrict__ bq, const float* __restrict__ bk, const float* __restrict__ bv,
    bf16* __restrict__ Qb, bf16* __restrict__ Kb, bf16* __restrict__ Vtb) {
  constexpr int K = 1024;
  __shared__ bf16 As[2][128 * 32];
  __shared__ bf16 Bs[2][128 * 32];
  const int z = blockIdx.z;
  const bf16* A  = (z == 0) ? xb : yb;
  const bf16* Bt = (z == 0) ? Wqt : (z == 1) ? Wkt : Wvt;
  const float* bias = (z == 0) ? bq : (z == 1) ? bk : bv;

  const int tid = threadIdx.x;
  const int wave = tid >> 6, lane = tid & 63;
  const int g = lane >> 4, r15 = lane & 15;
  const int m0 = blockIdx.x * 128, n0 = blockIdx.y * 128;
  const int wr = wave >> 1, wc = wave & 1;

  f32x4 acc[4][4] = {};

  const int c0 = tid, c1 = tid + 256;
  const int row0 = c0 >> 2, ch0 = c0 & 3;
  const int row1 = c1 >> 2, ch1 = c1 & 3;

  auto stage = [&](int buf, int k0) {
    gload_lds16(A  + (size_t)(m0 + row0) * K + k0 + ch0 * 8, (char*)As[buf] + c0 * 16);
    gload_lds16(Bt + (size_t)(n0 + row0) * K + k0 + ch0 * 8, (char*)Bs[buf] + c0 * 16);
    gload_lds16(A  + (size_t)(m0 + row1) * K + k0 + ch1 * 8, (char*)As[buf] + c1 * 16);
    gload_lds16(Bt + (size_t)(n0 + row1) * K + k0 + ch1 * 8, (char*)Bs[buf] + c1 * 16);
  };

  stage(0, 0);
  __syncthreads();
  int cur = 0;
  for (int t = 0; t < K / 32; ++t) {
    if (t + 1 < K / 32) stage(cur ^ 1, (t + 1) * 32);
    bf16x8 af[4], bfr[4];
#pragma unroll
    for (int mi = 0; mi < 4; ++mi)
      af[mi] = *(const bf16x8*)((const char*)As[cur] + ((wr * 64 + mi * 16 + r15) * 64 + g * 16));
#pragma unroll
    for (int nj = 0; nj < 4; ++nj)
      bfr[nj] = *(const bf16x8*)((const char*)Bs[cur] + ((wc * 64 + nj * 16 + r15) * 64 + g * 16));
#pragma unroll
    for (int mi = 0; mi < 4; ++mi)
#pragma unroll
      for (int nj = 0; nj < 4; ++nj)
        acc[mi][nj] = __builtin_amdgcn_mfma_f32_16x16x32_bf16(af[mi], bfr[nj], acc[mi][nj], 0, 0, 0);
    __syncthreads();
    cur ^= 1;
  }

#pragma unroll
  for (int mi = 0; mi < 4; ++mi) {
#pragma unroll
    for (int nj = 0; nj < 4; ++nj) {
      int row = m0 + wr * 64 + mi * 16 + g * 4;
      int col = n0 + wc * 64 + nj * 16 + r15;
      float bv_ = bias[col];
      if (z < 2) {
        bf16* C = (z == 0) ? Qb : Kb;
#pragma unroll
        for (int r = 0; r < 4; ++r)
          C[(size_t)(row + r) * 1024 + col] = (bf16)(acc[mi][nj][r] + bv_);
      } else {
        int b = row >> 11, n = row & 2047;
        bf16x4 pk;
#pragma unroll
        for (int r = 0; r < 4; ++r)
          pk[r] = (bf16)(acc[mi][nj][r] + bv_);
        *(bf16x4*)(Vtb + ((size_t)b * 1024 + col) * 2048 + n) = pk;
      }
    }
  }
}

// ---------------- out-projection GEMM, 128x64 tile (512 blocks), bias+ReLU, f32 out ----------------
__global__ __launch_bounds__(256) void gemm_out(
    const bf16* __restrict__ A, const bf16* __restrict__ Bt,
    const float* __restrict__ bias, float* __restrict__ C) {
  constexpr int K = 1024;
  __shared__ bf16 As[2][128 * 32];
  __shared__ bf16 Bs[2][64 * 32];
  const int tid = threadIdx.x;
  const int wave = tid >> 6, lane = tid & 63;
  const int g = lane >> 4, r15 = lane & 15;
  const int m0 = blockIdx.x * 128, n0 = blockIdx.y * 64;
  const int wr = wave >> 1, wc = wave & 1;  // wave tile 64x32

  f32x4 acc[4][2] = {};

  const int c0 = tid, c1 = tid + 256;
  const int row0 = c0 >> 2, ch0 = c0 & 3;
  const int row1 = c1 >> 2, ch1 = c1 & 3;

  auto stage = [&](int buf, int k0) {
    gload_lds16(A + (size_t)(m0 + row0) * K + k0 + ch0 * 8, (char*)As[buf] + c0 * 16);
    gload_lds16(A + (size_t)(m0 + row1) * K + k0 + ch1 * 8, (char*)As[buf] + c1 * 16);
    gload_lds16(Bt + (size_t)(n0 + row0) * K + k0 + ch0 * 8, (char*)Bs[buf] + c0 * 16);
  };

  stage(0, 0);
  __syncthreads();
  int cur = 0;
  for (int t = 0; t < K / 32; ++t) {
    if (t + 1 < K / 32) stage(cur ^ 1, (t + 1) * 32);
    bf16x8 af[4], bfr[2];
#pragma unroll
    for (int mi = 0; mi < 4; ++mi)
      af[mi] = *(const bf16x8*)((const char*)As[cur] + ((wr * 64 + mi * 16 + r15) * 64 + g * 16));
#pragma unroll
    for (int nj = 0; nj < 2; ++nj)
      bfr[nj] = *(const bf16x8*)((const char*)Bs[cur] + ((wc * 32 + nj * 16 + r15) * 64 + g * 16));
#pragma unroll
    for (int mi = 0; mi < 4; ++mi)
#pragma unroll
      for (int nj = 0; nj < 2; ++nj)
        acc[mi][nj] = __builtin_amdgcn_mfma_f32_16x16x32_bf16(af[mi], bfr[nj], acc[mi][nj], 0, 0, 0);
    __syncthreads();
    cur ^= 1;
  }

#pragma unroll
  for (int mi = 0; mi < 4; ++mi)
#pragma unroll
    for (int nj = 0; nj < 2; ++nj) {
      int row = m0 + wr * 64 + mi * 16 + g * 4;
      int col = n0 + wc * 32 + nj * 16 + r15;
      float bv_ = bias[col];
#pragma unroll
      for (int r = 0; r < 4; ++r)
        C[(size_t)(row + r) * 1024 + col] = fmaxf(acc[mi][nj][r] + bv_, 0.0f);
    }
}

// ---------------- flash attention: Q-tile 64 (1024 blocks), dbuf K/V, swizzled 8KB P ----------------
// Q,K: [B][2048][1024] bf16. V^T: [B][1024][2048] bf16. Oa: [B][2048][1024] bf16.
__global__ __launch_bounds__(256, 4) void attn_kernel(
    const bf16* __restrict__ Q, const bf16* __restrict__ Kin,
    const bf16* __restrict__ Vt, bf16* __restrict__ Oa) {
  __shared__ bf16 Ks[2][64 * 64];
  __shared__ bf16 Vs[2][64 * 64];
  __shared__ char Ps[4][2048];
  const int tid = threadIdx.x;
  const int wave = tid >> 6, lane = tid & 63;
  const int g = lane >> 4, r15 = lane & 15;
  const int qt = blockIdx.x, bh = blockIdx.y;
  const int b = bh >> 4, h = bh & 15;
  const bf16* Qg = Q + ((size_t)b * 2048 + qt * 64) * 1024 + h * 64;
  const bf16* Kg = Kin + (size_t)b * 2048 * 1024 + h * 64;
  const bf16* Vg = Vt + ((size_t)b * 1024 + h * 64) * 2048;

  // Q fragments (16 rows per wave) hoisted for the whole KV loop
  bf16x8 qf_[2];
#pragma unroll
  for (int kb = 0; kb < 2; ++kb)
    qf_[kb] = *(const bf16x8*)(Qg + (size_t)(wave * 16 + r15) * 1024 + kb * 32 + g * 8);

  f32x4 o[4] = {};
  float ls[4] = {};
  const float scale = 0.022097086912079612f;  // 1/sqrt(2048)

  const int c0 = tid, c1 = tid + 256;
  const int srow0 = c0 >> 3, sch0 = (c0 & 7) ^ (srow0 & 7);  // pre-swizzled global source chunk
  const int srow1 = c1 >> 3, sch1 = (c1 & 7) ^ (srow1 & 7);

  auto stage = [&](int buf, int kv0) {
    gload_lds16(Kg + (size_t)(kv0 + srow0) * 1024 + sch0 * 8, (char*)Ks[buf] + c0 * 16);
    gload_lds16(Vg + (size_t)srow0 * 2048 + kv0 + sch0 * 8, (char*)Vs[buf] + c0 * 16);
    gload_lds16(Kg + (size_t)(kv0 + srow1) * 1024 + sch1 * 8, (char*)Ks[buf] + c1 * 16);
    gload_lds16(Vg + (size_t)srow1 * 2048 + kv0 + sch1 * 8, (char*)Vs[buf] + c1 * 16);
  };

  stage(0, 0);
  __syncthreads();
  int cur = 0;
  char* Pw = Ps[wave];

  for (int t = 0; t < 32; ++t) {
    if (t < 31) stage(cur ^ 1, (t + 1) * 64);

    // S = Q K^T : 16 q-rows x 64 kv per wave
    f32x4 s[4] = {};
    __builtin_amdgcn_s_setprio(1);
#pragma unroll
    for (int kvf = 0; kvf < 4; ++kvf) {
      int row = kvf * 16 + r15;
#pragma unroll
      for (int kb = 0; kb < 2; ++kb) {
        int ch = (kb * 4 + g) ^ (row & 7);
        bf16x8 kf = *(const bf16x8*)((const char*)Ks[cur] + row * 128 + ch * 16);
        s[kvf] = __builtin_amdgcn_mfma_f32_16x16x32_bf16(qf_[kb], kf, s[kvf], 0, 0, 0);
      }
    }
    __builtin_amdgcn_s_setprio(0);

    // P = exp(s*scale): C-frag -> swizzled wave-private LDS -> A-frag; f32 row-sum partials
#pragma unroll
    for (int kvf = 0; kvf < 4; ++kvf)
#pragma unroll
      for (int r = 0; r < 4; ++r) {
        float p = __expf(s[kvf][r] * scale);
        ls[r] += p;
        int prow = g * 4 + r;
        int colb = (kvf * 16 + r15) * 2;
        *(bf16*)(Pw + prow * 128 + (colb ^ ((prow & 7) << 4))) = (bf16)p;
      }

    bf16x8 pa[2];
#pragma unroll
    for (int kb = 0; kb < 2; ++kb)
      pa[kb] = *(const bf16x8*)(Pw + r15 * 128 + ((kb * 64 + g * 16) ^ ((r15 & 7) << 4)));

    __builtin_amdgcn_s_setprio(1);
#pragma unroll
    for (int dvf = 0; dvf < 4; ++dvf) {
      int row = dvf * 16 + r15;
#pragma unroll
      for (int kb = 0; kb < 2; ++kb) {
        int ch = (kb * 4 + g) ^ (row & 7);
        bf16x8 vb = *(const bf16x8*)((const char*)Vs[cur] + row * 128 + ch * 16);
        o[dvf] = __builtin_amdgcn_mfma_f32_16x16x32_bf16(pa[kb], vb, o[dvf], 0, 0, 0);
      }
    }
    __builtin_amdgcn_s_setprio(0);

    __syncthreads();
    cur ^= 1;
  }

  // full row sums: reduce across the 16 lanes sharing g
#pragma unroll
  for (int r = 0; r < 4; ++r) {
    float v = ls[r];
    v += __shfl_xor(v, 1);
    v += __shfl_xor(v, 2);
    v += __shfl_xor(v, 4);
    v += __shfl_xor(v, 8);
    ls[r] = v;
  }

#pragma unroll
  for (int dvf = 0; dvf < 4; ++dvf)
#pragma unroll
    for (int r = 0; r < 4; ++r) {
      float val = o[dvf][r] / ls[r];
      size_t row = (size_t)b * 2048 + qt * 64 + wave * 16 + g * 4 + r;
      Oa[row * 1024 + h * 64 + dvf * 16 + r15] = (bf16)val;
    }
}

extern "C" void kernel_launch(void* const* d_in, const int* in_sizes, int n_in,
                              void* d_out, int out_size, void* d_ws, size_t ws_size,
                              hipStream_t stream) {
  (void)in_sizes; (void)n_in; (void)out_size; (void)ws_size;
  const float* x  = (const float*)d_in[0];
  const float* y  = (const float*)d_in[1];
  const float* Wq = (const float*)d_in[2];
  const float* bq = (const float*)d_in[3];
  const float* Wk = (const float*)d_in[4];
  const float* bk = (const float*)d_in[5];
  const float* Wv = (const float*)d_in[6];
  const float* bv = (const float*)d_in[7];
  const float* Wo = (const float*)d_in[8];
  const float* bo = (const float*)d_in[9];

  char* ws = (char*)d_ws;
  bf16* xb  = (bf16*)(ws + 0);
  bf16* yb  = (bf16*)(ws + 8388608);
  bf16* Qb  = (bf16*)(ws + 16777216);
  bf16* Kb  = (bf16*)(ws + 25165824);
  bf16* Vtb = (bf16*)(ws + 33554432);
  bf16* Oab = (bf16*)(ws + 41943040);
  bf16* Wqt = (bf16*)(ws + 50331648);
  bf16* Wkt = (bf16*)(ws + 52428800);
  bf16* Wvt = (bf16*)(ws + 54525952);
  bf16* Wot = (bf16*)(ws + 56623104);

  const int n4 = 4096 * 1024 / 4;
  cvt2_kernel<<<2 * n4 / 256, 256, 0, stream>>>((const float4*)x, (const float4*)y,
                                                (bf16x4*)xb, (bf16x4*)yb, n4);
  wtrans_kernel<<<dim3(32, 32, 4), dim3(32, 8), 0, stream>>>(Wq, Wk, Wv, Wo, Wqt, Wkt, Wvt, Wot);
  gemm_qkv<<<dim3(32, 8, 3), 256, 0, stream>>>(xb, yb, Wqt, Wkt, Wvt, bq, bk, bv, Qb, Kb, Vtb);
  attn_kernel<<<dim3(32, 32), 256, 0, stream>>>(Qb, Kb, Vtb, Oab);
  gemm_out<<<dim3(32, 16), 256, 0, stream>>>(Oab, Wot, bo, (float*)d_out);
}

// Round 3
// 141.587 us; speedup vs baseline: 1.2175x; 1.0094x over previous
//
#include <hip/hip_runtime.h>
#include <hip/hip_bf16.h>

typedef __bf16 bf16;
typedef __attribute__((ext_vector_type(8))) __bf16 bf16x8;
typedef __attribute__((ext_vector_type(4))) __bf16 bf16x4;
typedef __attribute__((ext_vector_type(4))) float f32x4;
typedef __attribute__((ext_vector_type(16))) float f32x16;
typedef __attribute__((ext_vector_type(4))) unsigned int u32x4;

__device__ __forceinline__ void gload_lds16(const void* g, void* l) {
  __builtin_amdgcn_global_load_lds((const __attribute__((address_space(1))) void*)g,
                                   (__attribute__((address_space(3))) void*)l, 16, 0, 0);
}

__device__ __forceinline__ float exp2_fast(float x) {
  float r;
  asm("v_exp_f32 %0, %1" : "=v"(r) : "v"(x));
  return r;
}

__device__ __forceinline__ unsigned pk2(float a, float b) {
  unsigned short lo = __builtin_bit_cast(unsigned short, (bf16)a);
  unsigned short hi = __builtin_bit_cast(unsigned short, (bf16)b);
  return (unsigned)lo | ((unsigned)hi << 16);
}

// ---------------- f32 -> bf16 convert, x and y in one launch ----------------
__global__ __launch_bounds__(256) void cvt2_kernel(const float4* __restrict__ a,
                                                   const float4* __restrict__ b,
                                                   bf16x4* __restrict__ oa,
                                                   bf16x4* __restrict__ ob, int n4) {
  int i = blockIdx.x * 256 + threadIdx.x;
  const float4* in = a; bf16x4* out = oa;
  if (i >= n4) { in = b; out = ob; i -= n4; }
  float4 v = in[i];
  bf16x4 o;
  o[0] = (bf16)v.x; o[1] = (bf16)v.y; o[2] = (bf16)v.z; o[3] = (bf16)v.w;
  out[i] = o;
}

// ---------------- transpose+convert 1024x1024 weights: T[n][k] = bf16(W[k][n]) ----------------
__global__ __launch_bounds__(256) void wtrans_kernel(
    const float* __restrict__ W0, const float* __restrict__ W1,
    const float* __restrict__ W2, const float* __restrict__ W3,
    bf16* __restrict__ T0, bf16* __restrict__ T1,
    bf16* __restrict__ T2, bf16* __restrict__ T3) {
  const float* W; bf16* T;
  switch (blockIdx.z) {
    case 0: W = W0; T = T0; break;
    case 1: W = W1; T = T1; break;
    case 2: W = W2; T = T2; break;
    default: W = W3; T = T3; break;
  }
  __shared__ float t[32][33];
  int tx = threadIdx.x, ty = threadIdx.y;
  int bn = blockIdx.x * 32, bk = blockIdx.y * 32;
#pragma unroll
  for (int i = 0; i < 32; i += 8)
    t[ty + i][tx] = W[(size_t)(bk + ty + i) * 1024 + bn + tx];
  __syncthreads();
#pragma unroll
  for (int i = 0; i < 32; i += 8)
    T[(size_t)(bn + ty + i) * 1024 + bk + tx] = (bf16)t[tx][ty + i];
}

// ---------------- merged Q/K/V projection GEMM, 128x128 tile, double-buffered ----------------
// z=0: Q = (xb*Wqt+bq)*QSCALE (bf16, prescaled by log2e/sqrt(2048)); z=1: K; z=2: V transposed.
__global__ __launch_bounds__(256) void gemm_qkv(
    const bf16* __restrict__ xb, const bf16* __restrict__ yb,
    const bf16* __restrict__ Wqt, const bf16* __restrict__ Wkt, const bf16* __restrict__ Wvt,
    const float* __restrict__ bq, const float* __restrict__ bk, const float* __restrict__ bv,
    bf16* __restrict__ Qb, bf16* __restrict__ Kb, bf16* __restrict__ Vtb) {
  constexpr int K = 1024;
  constexpr float QSCALE = (float)(1.4426950408889634 / 45.254833995939045);
  __shared__ bf16 As[2][128 * 32];
  __shared__ bf16 Bs[2][128 * 32];
  const int z = blockIdx.z;
  const bf16* A  = (z == 0) ? xb : yb;
  const bf16* Bt = (z == 0) ? Wqt : (z == 1) ? Wkt : Wvt;
  const float* bias = (z == 0) ? bq : (z == 1) ? bk : bv;

  const int tid = threadIdx.x;
  const int wave = tid >> 6, lane = tid & 63;
  const int g = lane >> 4, r15 = lane & 15;
  const int m0 = blockIdx.x * 128, n0 = blockIdx.y * 128;
  const int wr = wave >> 1, wc = wave & 1;

  f32x4 acc[4][4] = {};

  const int c0 = tid, c1 = tid + 256;
  const int row0 = c0 >> 2, ch0 = c0 & 3;
  const int row1 = c1 >> 2, ch1 = c1 & 3;

  auto stage = [&](int buf, int k0) {
    gload_lds16(A  + (size_t)(m0 + row0) * K + k0 + ch0 * 8, (char*)As[buf] + c0 * 16);
    gload_lds16(Bt + (size_t)(n0 + row0) * K + k0 + ch0 * 8, (char*)Bs[buf] + c0 * 16);
    gload_lds16(A  + (size_t)(m0 + row1) * K + k0 + ch1 * 8, (char*)As[buf] + c1 * 16);
    gload_lds16(Bt + (size_t)(n0 + row1) * K + k0 + ch1 * 8, (char*)Bs[buf] + c1 * 16);
  };

  stage(0, 0);
  __syncthreads();
  int cur = 0;
  for (int t = 0; t < K / 32; ++t) {
    if (t + 1 < K / 32) stage(cur ^ 1, (t + 1) * 32);
    bf16x8 af[4], bfr[4];
#pragma unroll
    for (int mi = 0; mi < 4; ++mi)
      af[mi] = *(const bf16x8*)((const char*)As[cur] + ((wr * 64 + mi * 16 + r15) * 64 + g * 16));
#pragma unroll
    for (int nj = 0; nj < 4; ++nj)
      bfr[nj] = *(const bf16x8*)((const char*)Bs[cur] + ((wc * 64 + nj * 16 + r15) * 64 + g * 16));
#pragma unroll
    for (int mi = 0; mi < 4; ++mi)
#pragma unroll
      for (int nj = 0; nj < 4; ++nj)
        acc[mi][nj] = __builtin_amdgcn_mfma_f32_16x16x32_bf16(af[mi], bfr[nj], acc[mi][nj], 0, 0, 0);
    __syncthreads();
    cur ^= 1;
  }

  const float scl = (z == 0) ? QSCALE : 1.0f;
#pragma unroll
  for (int mi = 0; mi < 4; ++mi) {
#pragma unroll
    for (int nj = 0; nj < 4; ++nj) {
      int row = m0 + wr * 64 + mi * 16 + g * 4;
      int col = n0 + wc * 64 + nj * 16 + r15;
      float bv_ = bias[col];
      if (z < 2) {
        bf16* C = (z == 0) ? Qb : Kb;
#pragma unroll
        for (int r = 0; r < 4; ++r)
          C[(size_t)(row + r) * 1024 + col] = (bf16)((acc[mi][nj][r] + bv_) * scl);
      } else {
        int b = row >> 11, n = row & 2047;
        bf16x4 pkv;
#pragma unroll
        for (int r = 0; r < 4; ++r)
          pkv[r] = (bf16)(acc[mi][nj][r] + bv_);
        *(bf16x4*)(Vtb + ((size_t)b * 1024 + col) * 2048 + n) = pkv;
      }
    }
  }
}

// ---------------- out-projection GEMM, 128x64 tile, bias+ReLU, f32 out ----------------
__global__ __launch_bounds__(256) void gemm_out(
    const bf16* __restrict__ A, const bf16* __restrict__ Bt,
    const float* __restrict__ bias, float* __restrict__ C) {
  constexpr int K = 1024;
  __shared__ bf16 As[2][128 * 32];
  __shared__ bf16 Bs[2][64 * 32];
  const int tid = threadIdx.x;
  const int wave = tid >> 6, lane = tid & 63;
  const int g = lane >> 4, r15 = lane & 15;
  const int m0 = blockIdx.x * 128, n0 = blockIdx.y * 64;
  const int wr = wave >> 1, wc = wave & 1;

  f32x4 acc[4][2] = {};

  const int c0 = tid, c1 = tid + 256;
  const int row0 = c0 >> 2, ch0 = c0 & 3;
  const int row1 = c1 >> 2, ch1 = c1 & 3;

  auto stage = [&](int buf, int k0) {
    gload_lds16(A + (size_t)(m0 + row0) * K + k0 + ch0 * 8, (char*)As[buf] + c0 * 16);
    gload_lds16(A + (size_t)(m0 + row1) * K + k0 + ch1 * 8, (char*)As[buf] + c1 * 16);
    gload_lds16(Bt + (size_t)(n0 + row0) * K + k0 + ch0 * 8, (char*)Bs[buf] + c0 * 16);
  };

  stage(0, 0);
  __syncthreads();
  int cur = 0;
  for (int t = 0; t < K / 32; ++t) {
    if (t + 1 < K / 32) stage(cur ^ 1, (t + 1) * 32);
    bf16x8 af[4], bfr[2];
#pragma unroll
    for (int mi = 0; mi < 4; ++mi)
      af[mi] = *(const bf16x8*)((const char*)As[cur] + ((wr * 64 + mi * 16 + r15) * 64 + g * 16));
#pragma unroll
    for (int nj = 0; nj < 2; ++nj)
      bfr[nj] = *(const bf16x8*)((const char*)Bs[cur] + ((wc * 32 + nj * 16 + r15) * 64 + g * 16));
#pragma unroll
    for (int mi = 0; mi < 4; ++mi)
#pragma unroll
      for (int nj = 0; nj < 2; ++nj)
        acc[mi][nj] = __builtin_amdgcn_mfma_f32_16x16x32_bf16(af[mi], bfr[nj], acc[mi][nj], 0, 0, 0);
    __syncthreads();
    cur ^= 1;
  }

#pragma unroll
  for (int mi = 0; mi < 4; ++mi)
#pragma unroll
    for (int nj = 0; nj < 2; ++nj) {
      int row = m0 + wr * 64 + mi * 16 + g * 4;
      int col = n0 + wc * 32 + nj * 16 + r15;
      float bv_ = bias[col];
#pragma unroll
      for (int r = 0; r < 4; ++r)
        C[(size_t)(row + r) * 1024 + col] = fmaxf(acc[mi][nj][r] + bv_, 0.0f);
    }
}

// ---------------- flash attention v3: swapped QK^T, 32x32 MFMA, in-register softmax ----------------
// Q prescaled by log2e/sqrt(2048). Q,K: [B][2048][1024] bf16. V^T: [B][1024][2048] bf16.
// Block: 128 threads = 2 waves, 64 q-rows (32/wave). Grid 1024 blocks, XCD-grouped.
__global__ __launch_bounds__(128, 2) void attn_kernel(
    const bf16* __restrict__ Q, const bf16* __restrict__ Kin,
    const bf16* __restrict__ Vt, bf16* __restrict__ Oa) {
  __shared__ bf16 Ks[2][64 * 64];
  __shared__ bf16 Vs[2][64 * 64];
  const int tid = threadIdx.x;
  const int wave = tid >> 6, lane = tid & 63;
  const int q5 = lane & 31, h = lane >> 5;

  // XCD-grouped mapping: each XCD owns 4 bh panels x 32 q-tiles (1024 = 8*4*32)
  int i = blockIdx.y * 32 + blockIdx.x;
  int xcd = i & 7, slot = i >> 3;
  int bh = xcd * 4 + (slot >> 5), qt = slot & 31;
  int b = bh >> 4, hd = bh & 15;

  const bf16* Qg = Q + ((size_t)b * 2048 + qt * 64 + wave * 32) * 1024 + hd * 64;
  const bf16* Kg = Kin + (size_t)b * 2048 * 1024 + hd * 64;
  const bf16* Vg = Vt + ((size_t)b * 1024 + hd * 64) * 2048;

  // Q B-fragments: lane holds Q[q=q5][k=16*ks+8*h+j], j=0..7
  bf16x8 qf[4];
#pragma unroll
  for (int ks = 0; ks < 4; ++ks)
    qf[ks] = *(const bf16x8*)(Qg + (size_t)q5 * 1024 + ks * 16 + h * 8);

  f32x16 o0 = {}, o1 = {};
  float ls = 0.0f;

  auto stage = [&](int buf, int kv0) {
#pragma unroll
    for (int ii = 0; ii < 4; ++ii) {
      int c = tid + ii * 128;
      int row = c >> 3, ch = (c & 7) ^ (row & 7);  // pre-swizzled global source chunk
      gload_lds16(Kg + (size_t)(kv0 + row) * 1024 + ch * 8, (char*)Ks[buf] + c * 16);
      gload_lds16(Vg + (size_t)row * 2048 + kv0 + ch * 8, (char*)Vs[buf] + c * 16);
    }
  };

  stage(0, 0);
  __syncthreads();
  int cur = 0;

  for (int t = 0; t < 32; ++t) {
    if (t < 31) stage(cur ^ 1, (t + 1) * 64);

    // S^T = K * Q^T : D[kv][q], col = q = q5, rows = kv (16 regs x 2 kv-blocks)
    f32x16 s0 = {}, s1 = {};
    __builtin_amdgcn_s_setprio(1);
#pragma unroll
    for (int ks = 0; ks < 4; ++ks) {
      int chk = ((2 * ks + h) ^ (q5 & 7)) * 16;
      bf16x8 k0 = *(const bf16x8*)((const char*)Ks[cur] + q5 * 128 + chk);
      bf16x8 k1 = *(const bf16x8*)((const char*)Ks[cur] + (q5 + 32) * 128 + chk);
      s0 = __builtin_amdgcn_mfma_f32_32x32x16_bf16(k0, qf[ks], s0, 0, 0, 0);
      s1 = __builtin_amdgcn_mfma_f32_32x32x16_bf16(k1, qf[ks], s1, 0, 0, 0);
    }
    __builtin_amdgcn_s_setprio(0);

    // P = exp2(S) in-register (Q prescaled); pack pairs to bf16 words; per-lane row-sum
    unsigned pw0[4][2], pw1[4][2];
#pragma unroll
    for (int g4 = 0; g4 < 4; ++g4) {
      float e0 = exp2_fast(s0[g4 * 4 + 0]), e1 = exp2_fast(s0[g4 * 4 + 1]);
      float e2 = exp2_fast(s0[g4 * 4 + 2]), e3 = exp2_fast(s0[g4 * 4 + 3]);
      float f0 = exp2_fast(s1[g4 * 4 + 0]), f1 = exp2_fast(s1[g4 * 4 + 1]);
      float f2 = exp2_fast(s1[g4 * 4 + 2]), f3 = exp2_fast(s1[g4 * 4 + 3]);
      ls += (e0 + e1) + (e2 + e3) + (f0 + f1) + (f2 + f3);
      pw0[g4][0] = pk2(e0, e1); pw0[g4][1] = pk2(e2, e3);
      pw1[g4][0] = pk2(f0, f1); pw1[g4][1] = pk2(f2, f3);
    }

    // PV: assemble P A-frag (kv = 16ks+8h+j) via half-wave exchange, then 2 MFMAs per ks
    __builtin_amdgcn_s_setprio(1);
#pragma unroll
    for (int ks = 0; ks < 4; ++ks) {
      const unsigned (*pw)[2] = (ks < 2) ? pw0 : pw1;  // kv-block = ks>>1 (compile-time)
      const int base = (ks & 1) * 2;
      unsigned a0 = pw[base][0], a1 = pw[base][1];
      unsigned b0 = pw[base + 1][0], b1 = pw[base + 1][1];
      unsigned s0w = h ? a0 : b0, s1w = h ? a1 : b1;  // send partner's needed group
      unsigned r0 = __shfl_xor(s0w, 32), r1 = __shfl_xor(s1w, 32);
      unsigned o0w = h ? b0 : a0, o1w = h ? b1 : a1;  // own kept group
      u32x4 w;
      w[0] = h ? r0 : o0w; w[1] = h ? r1 : o1w;
      w[2] = h ? o0w : r0; w[3] = h ? o1w : r1;
      bf16x8 pa = __builtin_bit_cast(bf16x8, w);
      int chk = ((2 * ks + h) ^ (q5 & 7)) * 16;
      bf16x8 v0 = *(const bf16x8*)((const char*)Vs[cur] + q5 * 128 + chk);
      bf16x8 v1 = *(const bf16x8*)((const char*)Vs[cur] + (q5 + 32) * 128 + chk);
      o0 = __builtin_amdgcn_mfma_f32_32x32x16_bf16(pa, v0, o0, 0, 0, 0);
      o1 = __builtin_amdgcn_mfma_f32_32x32x16_bf16(pa, v1, o1, 0, 0, 0);
    }
    __builtin_amdgcn_s_setprio(0);

    __syncthreads();
    cur ^= 1;
  }

  // finish: full row-sum (half-wave halves are complementary kv sets), divide, store
  ls += __shfl_xor(ls, 32);
  float inv = __builtin_amdgcn_rcpf(ls);

#pragma unroll
  for (int g4 = 0; g4 < 4; ++g4)
#pragma unroll
    for (int r = 0; r < 4; ++r) {
      int qr = g4 * 8 + 4 * h + r;            // O row for this reg
      float il = __shfl(inv, qr);             // inv for that q row lives in lane qr
      size_t row = (size_t)b * 2048 + qt * 64 + wave * 32 + qr;
      bf16* dst = Oa + row * 1024 + hd * 64;
      dst[q5]      = (bf16)(o0[g4 * 4 + r] * il);
      dst[q5 + 32] = (bf16)(o1[g4 * 4 + r] * il);
    }
}

extern "C" void kernel_launch(void* const* d_in, const int* in_sizes, int n_in,
                              void* d_out, int out_size, void* d_ws, size_t ws_size,
                              hipStream_t stream) {
  (void)in_sizes; (void)n_in; (void)out_size; (void)ws_size;
  const float* x  = (const float*)d_in[0];
  const float* y  = (const float*)d_in[1];
  const float* Wq = (const float*)d_in[2];
  const float* bq = (const float*)d_in[3];
  const float* Wk = (const float*)d_in[4];
  const float* bk = (const float*)d_in[5];
  const float* Wv = (const float*)d_in[6];
  const float* bv = (const float*)d_in[7];
  const float* Wo = (const float*)d_in[8];
  const float* bo = (const float*)d_in[9];

  char* ws = (char*)d_ws;
  bf16* xb  = (bf16*)(ws + 0);
  bf16* yb  = (bf16*)(ws + 8388608);
  bf16* Qb  = (bf16*)(ws + 16777216);
  bf16* Kb  = (bf16*)(ws + 25165824);
  bf16* Vtb = (bf16*)(ws + 33554432);
  bf16* Oab = (bf16*)(ws + 41943040);
  bf16* Wqt = (bf16*)(ws + 50331648);
  bf16* Wkt = (bf16*)(ws + 52428800);
  bf16* Wvt = (bf16*)(ws + 54525952);
  bf16* Wot = (bf16*)(ws + 56623104);

  const int n4 = 4096 * 1024 / 4;
  cvt2_kernel<<<2 * n4 / 256, 256, 0, stream>>>((const float4*)x, (const float4*)y,
                                                (bf16x4*)xb, (bf16x4*)yb, n4);
  wtrans_kernel<<<dim3(32, 32, 4), dim3(32, 8), 0, stream>>>(Wq, Wk, Wv, Wo, Wqt, Wkt, Wvt, Wot);
  gemm_qkv<<<dim3(32, 8, 3), 256, 0, stream>>>(xb, yb, Wqt, Wkt, Wvt, bq, bk, bv, Qb, Kb, Vtb);
  attn_kernel<<<dim3(32, 32), dim3(128), 0, stream>>>(Qb, Kb, Vtb, Oab);
  gemm_out<<<dim3(32, 16), 256, 0, stream>>>(Oab, Wot, bo, (float*)d_out);
}

// Round 4
// 131.583 us; speedup vs baseline: 1.3100x; 1.0760x over previous
//
#include <hip/hip_runtime.h>
#include <hip/hip_bf16.h>

typedef __bf16 bf16;
typedef __attribute__((ext_vector_type(8))) __bf16 bf16x8;
typedef __attribute__((ext_vector_type(4))) __bf16 bf16x4;
typedef __attribute__((ext_vector_type(4))) float f32x4;
typedef __attribute__((ext_vector_type(16))) float f32x16;
typedef __attribute__((ext_vector_type(4))) unsigned int u32x4;

__device__ __forceinline__ void gload_lds16(const void* g, void* l) {
  __builtin_amdgcn_global_load_lds((const __attribute__((address_space(1))) void*)g,
                                   (__attribute__((address_space(3))) void*)l, 16, 0, 0);
}

__device__ __forceinline__ float exp2_fast(float x) {
  float r;
  asm("v_exp_f32 %0, %1" : "=v"(r) : "v"(x));
  return r;
}

__device__ __forceinline__ unsigned cvtpk(float lo, float hi) {
  unsigned r;
  asm("v_cvt_pk_bf16_f32 %0, %1, %2" : "=v"(r) : "v"(lo), "v"(hi));
  return r;
}

__device__ __forceinline__ void plswap(unsigned& a, unsigned& b) {
  asm("v_permlane32_swap_b32 %0, %1" : "+v"(a), "+v"(b));
}

// ---------------- merged f32->bf16 convert (x,y) + weight transpose-convert ----------------
__global__ __launch_bounds__(256) void cvtw_kernel(
    const float* __restrict__ x, const float* __restrict__ y,
    bf16* __restrict__ xb, bf16* __restrict__ yb,
    const float* __restrict__ W0, const float* __restrict__ W1,
    const float* __restrict__ W2, const float* __restrict__ W3,
    bf16* __restrict__ T0, bf16* __restrict__ T1,
    bf16* __restrict__ T2, bf16* __restrict__ T3) {
  __shared__ float t[32][33];
  const int bid = blockIdx.x, tid = threadIdx.x;
  if (bid < 4096) {
    const int z = bid >> 10, rem = bid & 1023;
    const int bx = rem & 31, by = rem >> 5;
    const float* W; bf16* T;
    switch (z) {
      case 0: W = W0; T = T0; break;
      case 1: W = W1; T = T1; break;
      case 2: W = W2; T = T2; break;
      default: W = W3; T = T3; break;
    }
    const int tx = tid & 31, ty = tid >> 5;
    const int bn = bx * 32, bk = by * 32;
#pragma unroll
    for (int i = 0; i < 32; i += 8)
      t[ty + i][tx] = W[(size_t)(bk + ty + i) * 1024 + bn + tx];
    __syncthreads();
#pragma unroll
    for (int i = 0; i < 32; i += 8)
      T[(size_t)(bn + ty + i) * 1024 + bk + tx] = (bf16)t[tx][ty + i];
  } else {
    const int n4 = 1048576;
    int i = (bid - 4096) * 256 + tid;
    const float4* in = (const float4*)x; bf16x4* out = (bf16x4*)xb;
    if (i >= n4) { in = (const float4*)y; out = (bf16x4*)yb; i -= n4; }
    float4 v = in[i];
    bf16x4 o;
    o[0] = (bf16)v.x; o[1] = (bf16)v.y; o[2] = (bf16)v.z; o[3] = (bf16)v.w;
    out[i] = o;
  }
}

// ---------------- merged Q/K/V projection GEMM, 128x128 tile, double-buffered ----------------
// z=0: Q = (xb*Wqt+bq)*QSCALE (bf16, prescaled by log2e/sqrt(2048)); z=1: K; z=2: V transposed.
__global__ __launch_bounds__(256) void gemm_qkv(
    const bf16* __restrict__ xb, const bf16* __restrict__ yb,
    const bf16* __restrict__ Wqt, const bf16* __restrict__ Wkt, const bf16* __restrict__ Wvt,
    const float* __restrict__ bq, const float* __restrict__ bk, const float* __restrict__ bv,
    bf16* __restrict__ Qb, bf16* __restrict__ Kb, bf16* __restrict__ Vtb) {
  constexpr int K = 1024;
  constexpr float QSCALE = (float)(1.4426950408889634 / 45.254833995939045);
  __shared__ bf16 As[2][128 * 32];
  __shared__ bf16 Bs[2][128 * 32];
  const int z = blockIdx.z;
  const bf16* A  = (z == 0) ? xb : yb;
  const bf16* Bt = (z == 0) ? Wqt : (z == 1) ? Wkt : Wvt;
  const float* bias = (z == 0) ? bq : (z == 1) ? bk : bv;

  const int tid = threadIdx.x;
  const int wave = tid >> 6, lane = tid & 63;
  const int g = lane >> 4, r15 = lane & 15;
  const int m0 = blockIdx.x * 128, n0 = blockIdx.y * 128;
  const int wr = wave >> 1, wc = wave & 1;

  f32x4 acc[4][4] = {};

  const int c0 = tid, c1 = tid + 256;
  const int row0 = c0 >> 2, ch0 = c0 & 3;
  const int row1 = c1 >> 2, ch1 = c1 & 3;

  auto stage = [&](int buf, int k0) {
    gload_lds16(A  + (size_t)(m0 + row0) * K + k0 + ch0 * 8, (char*)As[buf] + c0 * 16);
    gload_lds16(Bt + (size_t)(n0 + row0) * K + k0 + ch0 * 8, (char*)Bs[buf] + c0 * 16);
    gload_lds16(A  + (size_t)(m0 + row1) * K + k0 + ch1 * 8, (char*)As[buf] + c1 * 16);
    gload_lds16(Bt + (size_t)(n0 + row1) * K + k0 + ch1 * 8, (char*)Bs[buf] + c1 * 16);
  };

  stage(0, 0);
  __syncthreads();
  int cur = 0;
  for (int t = 0; t < K / 32; ++t) {
    if (t + 1 < K / 32) stage(cur ^ 1, (t + 1) * 32);
    bf16x8 af[4], bfr[4];
#pragma unroll
    for (int mi = 0; mi < 4; ++mi)
      af[mi] = *(const bf16x8*)((const char*)As[cur] + ((wr * 64 + mi * 16 + r15) * 64 + g * 16));
#pragma unroll
    for (int nj = 0; nj < 4; ++nj)
      bfr[nj] = *(const bf16x8*)((const char*)Bs[cur] + ((wc * 64 + nj * 16 + r15) * 64 + g * 16));
#pragma unroll
    for (int mi = 0; mi < 4; ++mi)
#pragma unroll
      for (int nj = 0; nj < 4; ++nj)
        acc[mi][nj] = __builtin_amdgcn_mfma_f32_16x16x32_bf16(af[mi], bfr[nj], acc[mi][nj], 0, 0, 0);
    __syncthreads();
    cur ^= 1;
  }

  const float scl = (z == 0) ? QSCALE : 1.0f;
#pragma unroll
  for (int mi = 0; mi < 4; ++mi) {
#pragma unroll
    for (int nj = 0; nj < 4; ++nj) {
      int row = m0 + wr * 64 + mi * 16 + g * 4;
      int col = n0 + wc * 64 + nj * 16 + r15;
      float bv_ = bias[col];
      if (z < 2) {
        bf16* C = (z == 0) ? Qb : Kb;
#pragma unroll
        for (int r = 0; r < 4; ++r)
          C[(size_t)(row + r) * 1024 + col] = (bf16)((acc[mi][nj][r] + bv_) * scl);
      } else {
        int b = row >> 11, n = row & 2047;
        bf16x4 pkv;
#pragma unroll
        for (int r = 0; r < 4; ++r)
          pkv[r] = (bf16)(acc[mi][nj][r] + bv_);
        *(bf16x4*)(Vtb + ((size_t)b * 1024 + col) * 2048 + n) = pkv;
      }
    }
  }
}

// ---------------- out-projection GEMM, 128x64 tile, bias+ReLU, f32 out ----------------
__global__ __launch_bounds__(256) void gemm_out(
    const bf16* __restrict__ A, const bf16* __restrict__ Bt,
    const float* __restrict__ bias, float* __restrict__ C) {
  constexpr int K = 1024;
  __shared__ bf16 As[2][128 * 32];
  __shared__ bf16 Bs[2][64 * 32];
  const int tid = threadIdx.x;
  const int wave = tid >> 6, lane = tid & 63;
  const int g = lane >> 4, r15 = lane & 15;
  const int m0 = blockIdx.x * 128, n0 = blockIdx.y * 64;
  const int wr = wave >> 1, wc = wave & 1;

  f32x4 acc[4][2] = {};

  const int c0 = tid, c1 = tid + 256;
  const int row0 = c0 >> 2, ch0 = c0 & 3;
  const int row1 = c1 >> 2, ch1 = c1 & 3;

  auto stage = [&](int buf, int k0) {
    gload_lds16(A + (size_t)(m0 + row0) * K + k0 + ch0 * 8, (char*)As[buf] + c0 * 16);
    gload_lds16(A + (size_t)(m0 + row1) * K + k0 + ch1 * 8, (char*)As[buf] + c1 * 16);
    gload_lds16(Bt + (size_t)(n0 + row0) * K + k0 + ch0 * 8, (char*)Bs[buf] + c0 * 16);
  };

  stage(0, 0);
  __syncthreads();
  int cur = 0;
  for (int t = 0; t < K / 32; ++t) {
    if (t + 1 < K / 32) stage(cur ^ 1, (t + 1) * 32);
    bf16x8 af[4], bfr[2];
#pragma unroll
    for (int mi = 0; mi < 4; ++mi)
      af[mi] = *(const bf16x8*)((const char*)As[cur] + ((wr * 64 + mi * 16 + r15) * 64 + g * 16));
#pragma unroll
    for (int nj = 0; nj < 2; ++nj)
      bfr[nj] = *(const bf16x8*)((const char*)Bs[cur] + ((wc * 32 + nj * 16 + r15) * 64 + g * 16));
#pragma unroll
    for (int mi = 0; mi < 4; ++mi)
#pragma unroll
      for (int nj = 0; nj < 2; ++nj)
        acc[mi][nj] = __builtin_amdgcn_mfma_f32_16x16x32_bf16(af[mi], bfr[nj], acc[mi][nj], 0, 0, 0);
    __syncthreads();
    cur ^= 1;
  }

#pragma unroll
  for (int mi = 0; mi < 4; ++mi)
#pragma unroll
    for (int nj = 0; nj < 2; ++nj) {
      int row = m0 + wr * 64 + mi * 16 + g * 4;
      int col = n0 + wc * 32 + nj * 16 + r15;
      float bv_ = bias[col];
#pragma unroll
      for (int r = 0; r < 4; ++r)
        C[(size_t)(row + r) * 1024 + col] = fmaxf(acc[mi][nj][r] + bv_, 0.0f);
    }
}

// ---------------- flash attention v4: kv-split waves, permlane exchange, cvt_pk ----------------
// Q prescaled by log2e/sqrt(2048). Q,K: [B][2048][1024] bf16. V^T: [B][1024][2048] bf16.
// Block: 128 threads = 2 waves; 64 q-rows/block; wave w owns kv rows [32w,32w+32) of each tile.
__global__ __launch_bounds__(128, 2) void attn_kernel(
    const bf16* __restrict__ Q, const bf16* __restrict__ Kin,
    const bf16* __restrict__ Vt, bf16* __restrict__ Oa) {
  __shared__ bf16 Ks[2][64 * 64];
  __shared__ bf16 Vs[2][64 * 64];
  __shared__ float lsh[2][2][32];
  const int tid = threadIdx.x;
  const int w = tid >> 6, lane = tid & 63;
  const int q5 = lane & 31, h = lane >> 5;

  // XCD-grouped mapping: each XCD owns 4 bh panels x 32 q-tiles
  int i = blockIdx.y * 32 + blockIdx.x;
  int xcd = i & 7, slot = i >> 3;
  int bh = xcd * 4 + (slot >> 5), qt = slot & 31;
  int b = bh >> 4, hd = bh & 15;

  const bf16* Qg = Q + ((size_t)b * 2048 + qt * 64) * 1024 + hd * 64;
  const bf16* Kg = Kin + (size_t)b * 2048 * 1024 + hd * 64;
  const bf16* Vg = Vt + ((size_t)b * 1024 + hd * 64) * 2048;

  // Q B-fragments for all 64 q rows: lane holds Q[q=qb*32+q5][k=16ks+8h+j]
  bf16x8 qf[2][4];
#pragma unroll
  for (int qb = 0; qb < 2; ++qb)
#pragma unroll
    for (int ks = 0; ks < 4; ++ks)
      qf[qb][ks] = *(const bf16x8*)(Qg + (size_t)(qb * 32 + q5) * 1024 + ks * 16 + h * 8);

  f32x16 o[2][2] = {};  // [qb][j]: j=0 -> own d-block (db=w), j=1 -> partner (db=1-w)
  float ls[2] = {};

  auto stage = [&](int buf, int kv0) {
#pragma unroll
    for (int ii = 0; ii < 4; ++ii) {
      int c = tid + ii * 128;
      int row = c >> 3;
      int sl = (c & 7) ^ (row & 7) ^ ((row >> 3) & 1);  // pre-swizzled global source chunk
      gload_lds16(Kg + (size_t)(kv0 + row) * 1024 + sl * 8, (char*)Ks[buf] + c * 16);
      gload_lds16(Vg + (size_t)row * 2048 + kv0 + sl * 8, (char*)Vs[buf] + c * 16);
    }
  };

  stage(0, 0);
  __syncthreads();
  int cur = 0;

  const int krow = w * 32 + q5;
  const int kswz = (krow & 7) ^ ((krow >> 3) & 1);

  for (int t = 0; t < 32; ++t) {
    if (t < 31) stage(cur ^ 1, (t + 1) * 64);

    // S^T = K_w * Q^T : rows kv-local 0-31, cols q (2 q-blocks)
    f32x16 s[2] = {};
    __builtin_amdgcn_s_setprio(1);
#pragma unroll
    for (int ks = 0; ks < 4; ++ks) {
      bf16x8 kf = *(const bf16x8*)((const char*)Ks[cur] + krow * 128 + (((2 * ks + h) ^ kswz) << 4));
      s[0] = __builtin_amdgcn_mfma_f32_32x32x16_bf16(kf, qf[0][ks], s[0], 0, 0, 0);
      s[1] = __builtin_amdgcn_mfma_f32_32x32x16_bf16(kf, qf[1][ks], s[1], 0, 0, 0);
    }
    __builtin_amdgcn_s_setprio(0);

    // P = exp2(S), pack to bf16 words, permlane half-exchange -> PV A-frags in place
    unsigned u[2][8];
#pragma unroll
    for (int qb = 0; qb < 2; ++qb) {
      float e[16];
#pragma unroll
      for (int j = 0; j < 16; ++j) e[j] = exp2_fast(s[qb][j]);
      ls[qb] += ((((e[0] + e[1]) + (e[2] + e[3])) + ((e[4] + e[5]) + (e[6] + e[7]))) +
                 (((e[8] + e[9]) + (e[10] + e[11])) + ((e[12] + e[13]) + (e[14] + e[15]))));
#pragma unroll
      for (int p = 0; p < 8; ++p) u[qb][p] = cvtpk(e[2 * p], e[2 * p + 1]);
      plswap(u[qb][0], u[qb][2]); plswap(u[qb][1], u[qb][3]);
      plswap(u[qb][4], u[qb][6]); plswap(u[qb][5], u[qb][7]);
    }

    // PV: o[qb][j] += P_A x V_B over wave's kv half (2 k-sub-steps)
    __builtin_amdgcn_s_setprio(1);
#pragma unroll
    for (int j = 0; j < 2; ++j) {
      const int db = w ^ j;
      const int vrow0 = db * 32 + q5;
      const int vswz = (vrow0 & 7) ^ ((vrow0 >> 3) & 1);
#pragma unroll
      for (int kap = 0; kap < 2; ++kap) {
        bf16x8 vb = *(const bf16x8*)((const char*)Vs[cur] + vrow0 * 128 +
                                     (((4 * w + 2 * kap + h) ^ vswz) << 4));
#pragma unroll
        for (int qb = 0; qb < 2; ++qb) {
          u32x4 uw;
          uw[0] = u[qb][4 * kap + 0]; uw[1] = u[qb][4 * kap + 1];
          uw[2] = u[qb][4 * kap + 2]; uw[3] = u[qb][4 * kap + 3];
          bf16x8 pa = __builtin_bit_cast(bf16x8, uw);
          o[qb][j] = __builtin_amdgcn_mfma_f32_32x32x16_bf16(pa, vb, o[qb][j], 0, 0, 0);
        }
      }
    }
    __builtin_amdgcn_s_setprio(0);

    __syncthreads();
    cur ^= 1;
  }

  // ls: cross-h reduce, publish per-wave to LDS
  ls[0] += __shfl_xor(ls[0], 32);
  ls[1] += __shfl_xor(ls[1], 32);
  if (h == 0) { lsh[w][0][q5] = ls[0]; lsh[w][1][q5] = ls[1]; }

  // cross-wave O combine: each wave publishes its partner-block partial via Ks (16 KB)
  float* osh = (float*)Ks;  // [2 waves][2 qb][64 lanes][16]
#pragma unroll
  for (int qb = 0; qb < 2; ++qb)
    *(f32x16*)(osh + ((w * 2 + qb) * 64 + lane) * 16) = o[qb][1];
  __syncthreads();

#pragma unroll
  for (int qb = 0; qb < 2; ++qb) {
    float lt = ls[qb] + lsh[1 - w][qb][q5];
    float iv = __builtin_amdgcn_rcpf(lt);
    f32x16 p = *(const f32x16*)(osh + (((1 - w) * 2 + qb) * 64 + lane) * 16);
#pragma unroll
    for (int g4 = 0; g4 < 4; ++g4)
#pragma unroll
      for (int r = 0; r < 4; ++r) {
        int qr = g4 * 8 + 4 * h + r;
        float il = __shfl(iv, qr);
        size_t row = (size_t)b * 2048 + qt * 64 + qb * 32 + qr;
        Oa[row * 1024 + hd * 64 + w * 32 + q5] = (bf16)((o[qb][0][g4 * 4 + r] + p[g4 * 4 + r]) * il);
      }
  }
}

extern "C" void kernel_launch(void* const* d_in, const int* in_sizes, int n_in,
                              void* d_out, int out_size, void* d_ws, size_t ws_size,
                              hipStream_t stream) {
  (void)in_sizes; (void)n_in; (void)out_size; (void)ws_size;
  const float* x  = (const float*)d_in[0];
  const float* y  = (const float*)d_in[1];
  const float* Wq = (const float*)d_in[2];
  const float* bq = (const float*)d_in[3];
  const float* Wk = (const float*)d_in[4];
  const float* bk = (const float*)d_in[5];
  const float* Wv = (const float*)d_in[6];
  const float* bv = (const float*)d_in[7];
  const float* Wo = (const float*)d_in[8];
  const float* bo = (const float*)d_in[9];

  char* ws = (char*)d_ws;
  bf16* xb  = (bf16*)(ws + 0);
  bf16* yb  = (bf16*)(ws + 8388608);
  bf16* Qb  = (bf16*)(ws + 16777216);
  bf16* Kb  = (bf16*)(ws + 25165824);
  bf16* Vtb = (bf16*)(ws + 33554432);
  bf16* Oab = (bf16*)(ws + 41943040);
  bf16* Wqt = (bf16*)(ws + 50331648);
  bf16* Wkt = (bf16*)(ws + 52428800);
  bf16* Wvt = (bf16*)(ws + 54525952);
  bf16* Wot = (bf16*)(ws + 56623104);

  cvtw_kernel<<<12288, 256, 0, stream>>>(x, y, xb, yb, Wq, Wk, Wv, Wo, Wqt, Wkt, Wvt, Wot);
  gemm_qkv<<<dim3(32, 8, 3), 256, 0, stream>>>(xb, yb, Wqt, Wkt, Wvt, bq, bk, bv, Qb, Kb, Vtb);
  attn_kernel<<<dim3(32, 32), dim3(128), 0, stream>>>(Qb, Kb, Vtb, Oab);
  gemm_out<<<dim3(32, 16), 256, 0, stream>>>(Oab, Wot, bo, (float*)d_out);
}

// Round 5
// 129.136 us; speedup vs baseline: 1.3349x; 1.0190x over previous
//
#include <hip/hip_runtime.h>
#include <hip/hip_bf16.h>

typedef __bf16 bf16;
typedef __attribute__((ext_vector_type(8))) __bf16 bf16x8;
typedef __attribute__((ext_vector_type(4))) __bf16 bf16x4;
typedef __attribute__((ext_vector_type(4))) float f32x4;
typedef __attribute__((ext_vector_type(16))) float f32x16;
typedef __attribute__((ext_vector_type(4))) unsigned int u32x4;

__device__ __forceinline__ void gload_lds16(const void* g, void* l) {
  __builtin_amdgcn_global_load_lds((const __attribute__((address_space(1))) void*)g,
                                   (__attribute__((address_space(3))) void*)l, 16, 0, 0);
}

__device__ __forceinline__ float exp2_fast(float x) {
  float r;
  asm("v_exp_f32 %0, %1" : "=v"(r) : "v"(x));
  return r;
}

__device__ __forceinline__ unsigned cvtpk(float lo, float hi) {
  unsigned r;
  asm("v_cvt_pk_bf16_f32 %0, %1, %2" : "=v"(r) : "v"(lo), "v"(hi));
  return r;
}

__device__ __forceinline__ void plswap(unsigned& a, unsigned& b) {
  asm("v_permlane32_swap_b32 %0, %1" : "+v"(a), "+v"(b));
}

// ---------------- merged f32->bf16 convert (x,y) + weight transpose-convert ----------------
__global__ __launch_bounds__(256) void cvtw_kernel(
    const float* __restrict__ x, const float* __restrict__ y,
    bf16* __restrict__ xb, bf16* __restrict__ yb,
    const float* __restrict__ W0, const float* __restrict__ W1,
    const float* __restrict__ W2, const float* __restrict__ W3,
    bf16* __restrict__ T0, bf16* __restrict__ T1,
    bf16* __restrict__ T2, bf16* __restrict__ T3) {
  __shared__ float t[32][33];
  const int bid = blockIdx.x, tid = threadIdx.x;
  if (bid < 4096) {
    const int z = bid >> 10, rem = bid & 1023;
    const int bx = rem & 31, by = rem >> 5;
    const float* W; bf16* T;
    switch (z) {
      case 0: W = W0; T = T0; break;
      case 1: W = W1; T = T1; break;
      case 2: W = W2; T = T2; break;
      default: W = W3; T = T3; break;
    }
    const int tx = tid & 31, ty = tid >> 5;
    const int bn = bx * 32, bk = by * 32;
#pragma unroll
    for (int i = 0; i < 32; i += 8)
      t[ty + i][tx] = W[(size_t)(bk + ty + i) * 1024 + bn + tx];
    __syncthreads();
#pragma unroll
    for (int i = 0; i < 32; i += 8)
      T[(size_t)(bn + ty + i) * 1024 + bk + tx] = (bf16)t[tx][ty + i];
  } else {
    const int n4 = 1048576;
    int i = (bid - 4096) * 256 + tid;
    const float4* in = (const float4*)x; bf16x4* out = (bf16x4*)xb;
    if (i >= n4) { in = (const float4*)y; out = (bf16x4*)yb; i -= n4; }
    float4 v = in[i];
    bf16x4 o;
    o[0] = (bf16)v.x; o[1] = (bf16)v.y; o[2] = (bf16)v.z; o[3] = (bf16)v.w;
    out[i] = o;
  }
}

// ---------------- merged Q/K/V projection GEMM, 128x128 tile, double-buffered ----------------
// z=0: Q = (xb*Wqt+bq)*QSCALE (bf16, prescaled by log2e/sqrt(2048)); z=1: K; z=2: V transposed.
__global__ __launch_bounds__(256) void gemm_qkv(
    const bf16* __restrict__ xb, const bf16* __restrict__ yb,
    const bf16* __restrict__ Wqt, const bf16* __restrict__ Wkt, const bf16* __restrict__ Wvt,
    const float* __restrict__ bq, const float* __restrict__ bk, const float* __restrict__ bv,
    bf16* __restrict__ Qb, bf16* __restrict__ Kb, bf16* __restrict__ Vtb) {
  constexpr int K = 1024;
  constexpr float QSCALE = (float)(1.4426950408889634 / 45.254833995939045);
  __shared__ bf16 As[2][128 * 32];
  __shared__ bf16 Bs[2][128 * 32];
  const int z = blockIdx.z;
  const bf16* A  = (z == 0) ? xb : yb;
  const bf16* Bt = (z == 0) ? Wqt : (z == 1) ? Wkt : Wvt;
  const float* bias = (z == 0) ? bq : (z == 1) ? bk : bv;

  const int tid = threadIdx.x;
  const int wave = tid >> 6, lane = tid & 63;
  const int g = lane >> 4, r15 = lane & 15;
  const int m0 = blockIdx.x * 128, n0 = blockIdx.y * 128;
  const int wr = wave >> 1, wc = wave & 1;

  f32x4 acc[4][4] = {};

  const int c0 = tid, c1 = tid + 256;
  const int row0 = c0 >> 2, ch0 = c0 & 3;
  const int row1 = c1 >> 2, ch1 = c1 & 3;

  auto stage = [&](int buf, int k0) {
    gload_lds16(A  + (size_t)(m0 + row0) * K + k0 + ch0 * 8, (char*)As[buf] + c0 * 16);
    gload_lds16(Bt + (size_t)(n0 + row0) * K + k0 + ch0 * 8, (char*)Bs[buf] + c0 * 16);
    gload_lds16(A  + (size_t)(m0 + row1) * K + k0 + ch1 * 8, (char*)As[buf] + c1 * 16);
    gload_lds16(Bt + (size_t)(n0 + row1) * K + k0 + ch1 * 8, (char*)Bs[buf] + c1 * 16);
  };

  stage(0, 0);
  __syncthreads();
  int cur = 0;
  for (int t = 0; t < K / 32; ++t) {
    if (t + 1 < K / 32) stage(cur ^ 1, (t + 1) * 32);
    bf16x8 af[4], bfr[4];
#pragma unroll
    for (int mi = 0; mi < 4; ++mi)
      af[mi] = *(const bf16x8*)((const char*)As[cur] + ((wr * 64 + mi * 16 + r15) * 64 + g * 16));
#pragma unroll
    for (int nj = 0; nj < 4; ++nj)
      bfr[nj] = *(const bf16x8*)((const char*)Bs[cur] + ((wc * 64 + nj * 16 + r15) * 64 + g * 16));
#pragma unroll
    for (int mi = 0; mi < 4; ++mi)
#pragma unroll
      for (int nj = 0; nj < 4; ++nj)
        acc[mi][nj] = __builtin_amdgcn_mfma_f32_16x16x32_bf16(af[mi], bfr[nj], acc[mi][nj], 0, 0, 0);
    __syncthreads();
    cur ^= 1;
  }

  const float scl = (z == 0) ? QSCALE : 1.0f;
#pragma unroll
  for (int mi = 0; mi < 4; ++mi) {
#pragma unroll
    for (int nj = 0; nj < 4; ++nj) {
      int row = m0 + wr * 64 + mi * 16 + g * 4;
      int col = n0 + wc * 64 + nj * 16 + r15;
      float bv_ = bias[col];
      if (z < 2) {
        bf16* C = (z == 0) ? Qb : Kb;
#pragma unroll
        for (int r = 0; r < 4; ++r)
          C[(size_t)(row + r) * 1024 + col] = (bf16)((acc[mi][nj][r] + bv_) * scl);
      } else {
        int b = row >> 11, n = row & 2047;
        bf16x4 pkv;
#pragma unroll
        for (int r = 0; r < 4; ++r)
          pkv[r] = (bf16)(acc[mi][nj][r] + bv_);
        *(bf16x4*)(Vtb + ((size_t)b * 1024 + col) * 2048 + n) = pkv;
      }
    }
  }
}

// ---------------- out-projection GEMM, 128x64 tile, bias+ReLU, f32 out ----------------
__global__ __launch_bounds__(256) void gemm_out(
    const bf16* __restrict__ A, const bf16* __restrict__ Bt,
    const float* __restrict__ bias, float* __restrict__ C) {
  constexpr int K = 1024;
  __shared__ bf16 As[2][128 * 32];
  __shared__ bf16 Bs[2][64 * 32];
  const int tid = threadIdx.x;
  const int wave = tid >> 6, lane = tid & 63;
  const int g = lane >> 4, r15 = lane & 15;
  const int m0 = blockIdx.x * 128, n0 = blockIdx.y * 64;
  const int wr = wave >> 1, wc = wave & 1;

  f32x4 acc[4][2] = {};

  const int c0 = tid, c1 = tid + 256;
  const int row0 = c0 >> 2, ch0 = c0 & 3;
  const int row1 = c1 >> 2, ch1 = c1 & 3;

  auto stage = [&](int buf, int k0) {
    gload_lds16(A + (size_t)(m0 + row0) * K + k0 + ch0 * 8, (char*)As[buf] + c0 * 16);
    gload_lds16(A + (size_t)(m0 + row1) * K + k0 + ch1 * 8, (char*)As[buf] + c1 * 16);
    gload_lds16(Bt + (size_t)(n0 + row0) * K + k0 + ch0 * 8, (char*)Bs[buf] + c0 * 16);
  };

  stage(0, 0);
  __syncthreads();
  int cur = 0;
  for (int t = 0; t < K / 32; ++t) {
    if (t + 1 < K / 32) stage(cur ^ 1, (t + 1) * 32);
    bf16x8 af[4], bfr[2];
#pragma unroll
    for (int mi = 0; mi < 4; ++mi)
      af[mi] = *(const bf16x8*)((const char*)As[cur] + ((wr * 64 + mi * 16 + r15) * 64 + g * 16));
#pragma unroll
    for (int nj = 0; nj < 2; ++nj)
      bfr[nj] = *(const bf16x8*)((const char*)Bs[cur] + ((wc * 32 + nj * 16 + r15) * 64 + g * 16));
#pragma unroll
    for (int mi = 0; mi < 4; ++mi)
#pragma unroll
      for (int nj = 0; nj < 2; ++nj)
        acc[mi][nj] = __builtin_amdgcn_mfma_f32_16x16x32_bf16(af[mi], bfr[nj], acc[mi][nj], 0, 0, 0);
    __syncthreads();
    cur ^= 1;
  }

#pragma unroll
  for (int mi = 0; mi < 4; ++mi)
#pragma unroll
    for (int nj = 0; nj < 2; ++nj) {
      int row = m0 + wr * 64 + mi * 16 + g * 4;
      int col = n0 + wc * 32 + nj * 16 + r15;
      float bv_ = bias[col];
#pragma unroll
      for (int r = 0; r < 4; ++r)
        C[(size_t)(row + r) * 1024 + col] = fmaxf(acc[mi][nj][r] + bv_, 0.0f);
    }
}

// ---------------- flash attention v5: kv-split waves + att[2] pipeline (PV one tile behind) ----
// Q prescaled by log2e/sqrt(2048). Q,K: [B][2048][1024] bf16. V^T: [B][1024][2048] bf16.
// Block: 128 threads = 2 waves; 64 q-rows/block; wave w owns kv rows [32w,32w+32) of each tile.
// Per iter: stage(t+1) | QK(t) | ldV(t)->regs | PV(t-1) (reg-fed) | exp/pack(t) | barrier.
__global__ __launch_bounds__(128, 2) void attn_kernel(
    const bf16* __restrict__ Q, const bf16* __restrict__ Kin,
    const bf16* __restrict__ Vt, bf16* __restrict__ Oa) {
  __shared__ bf16 Ks[2][64 * 64];
  __shared__ bf16 Vs[2][64 * 64];
  __shared__ float lsh[2][2][32];
  const int tid = threadIdx.x;
  const int w = tid >> 6, lane = tid & 63;
  const int q5 = lane & 31, h = lane >> 5;

  // XCD-grouped mapping: each XCD owns 4 bh panels x 32 q-tiles
  int i = blockIdx.y * 32 + blockIdx.x;
  int xcd = i & 7, slot = i >> 3;
  int bh = xcd * 4 + (slot >> 5), qt = slot & 31;
  int b = bh >> 4, hd = bh & 15;

  const bf16* Qg = Q + ((size_t)b * 2048 + qt * 64) * 1024 + hd * 64;
  const bf16* Kg = Kin + (size_t)b * 2048 * 1024 + hd * 64;
  const bf16* Vg = Vt + ((size_t)b * 1024 + hd * 64) * 2048;

  // Q B-fragments for all 64 q rows: lane holds Q[q=qb*32+q5][k=16ks+8h+j]
  bf16x8 qf[2][4];
#pragma unroll
  for (int qb = 0; qb < 2; ++qb)
#pragma unroll
    for (int ks = 0; ks < 4; ++ks)
      qf[qb][ks] = *(const bf16x8*)(Qg + (size_t)(qb * 32 + q5) * 1024 + ks * 16 + h * 8);

  f32x16 o[2][2] = {};  // [qb][j]: j=0 -> own d-block (db=w), j=1 -> partner (db=1-w)
  float ls[2] = {};

  auto stage = [&](int buf, int kv0) {
#pragma unroll
    for (int ii = 0; ii < 4; ++ii) {
      int c = tid + ii * 128;
      int row = c >> 3;
      int sl = (c & 7) ^ (row & 7) ^ ((row >> 3) & 1);  // pre-swizzled global source chunk
      gload_lds16(Kg + (size_t)(kv0 + row) * 1024 + sl * 8, (char*)Ks[buf] + c * 16);
      gload_lds16(Vg + (size_t)row * 2048 + kv0 + sl * 8, (char*)Vs[buf] + c * 16);
    }
  };

  stage(0, 0);
  __syncthreads();
  int cur = 0;

  const int krow = w * 32 + q5;
  const int kswz = (krow & 7) ^ ((krow >> 3) & 1);

  // two-deep pipeline state (static names — no runtime-indexed arrays)
  unsigned uA[2][8], uB[2][8];
  bf16x8 vA[4], vB[4];

  // one pipeline phase: QK(t) + ldV(t)->vout + PV(t-1) from uin/vin + exp/pack(t)->uout
  auto phase = [&](int t, unsigned (&uin)[2][8], unsigned (&uout)[2][8],
                   bf16x8 (&vin)[4], bf16x8 (&vout)[4], bool doStage, bool doPV) {
    if (doStage) stage(cur ^ 1, (t + 1) * 64);

    // S^T = K_w * Q^T
    f32x16 s[2] = {};
    __builtin_amdgcn_s_setprio(1);
#pragma unroll
    for (int ks = 0; ks < 4; ++ks) {
      bf16x8 kf = *(const bf16x8*)((const char*)Ks[cur] + krow * 128 + (((2 * ks + h) ^ kswz) << 4));
      s[0] = __builtin_amdgcn_mfma_f32_32x32x16_bf16(kf, qf[0][ks], s[0], 0, 0, 0);
      s[1] = __builtin_amdgcn_mfma_f32_32x32x16_bf16(kf, qf[1][ks], s[1], 0, 0, 0);
    }

    // V(t) fragments -> registers
#pragma unroll
    for (int j = 0; j < 2; ++j) {
      const int db = w ^ j;
      const int vrow0 = db * 32 + q5;
      const int vswz = (vrow0 & 7) ^ ((vrow0 >> 3) & 1);
#pragma unroll
      for (int kap = 0; kap < 2; ++kap)
        vout[2 * j + kap] = *(const bf16x8*)((const char*)Vs[cur] + vrow0 * 128 +
                                             (((4 * w + 2 * kap + h) ^ vswz) << 4));
    }

    // PV(t-1): fully register-fed, fills MFMA pipe while s(t) drains
    if (doPV) {
#pragma unroll
      for (int j = 0; j < 2; ++j)
#pragma unroll
        for (int kap = 0; kap < 2; ++kap)
#pragma unroll
          for (int qb = 0; qb < 2; ++qb) {
            u32x4 uw;
            uw[0] = uin[qb][4 * kap + 0]; uw[1] = uin[qb][4 * kap + 1];
            uw[2] = uin[qb][4 * kap + 2]; uw[3] = uin[qb][4 * kap + 3];
            bf16x8 pa = __builtin_bit_cast(bf16x8, uw);
            o[qb][j] = __builtin_amdgcn_mfma_f32_32x32x16_bf16(pa, vin[2 * j + kap], o[qb][j], 0, 0, 0);
          }
    }
    __builtin_amdgcn_s_setprio(0);

    // P(t) = exp2(S), pack, permlane half-exchange (VALU; overlaps PV(t-1) drain)
#pragma unroll
    for (int qb = 0; qb < 2; ++qb) {
      float e[16];
#pragma unroll
      for (int j = 0; j < 16; ++j) e[j] = exp2_fast(s[qb][j]);
      ls[qb] += ((((e[0] + e[1]) + (e[2] + e[3])) + ((e[4] + e[5]) + (e[6] + e[7]))) +
                 (((e[8] + e[9]) + (e[10] + e[11])) + ((e[12] + e[13]) + (e[14] + e[15]))));
#pragma unroll
      for (int p = 0; p < 8; ++p) uout[qb][p] = cvtpk(e[2 * p], e[2 * p + 1]);
      plswap(uout[qb][0], uout[qb][2]); plswap(uout[qb][1], uout[qb][3]);
      plswap(uout[qb][4], uout[qb][6]); plswap(uout[qb][5], uout[qb][7]);
    }

    __syncthreads();
    cur ^= 1;
  };

  // prologue: tile 0 (no PV)
  phase(0, uB, uA, vB, vA, true, false);
  // steady state: tiles 1..30 in pairs
  for (int t = 1; t < 31; t += 2) {
    phase(t, uA, uB, vA, vB, true, true);
    phase(t + 1, uB, uA, vB, vA, true, true);
  }
  // tail: tile 31 (no stage), then final PV(31)
  phase(31, uA, uB, vA, vB, false, true);
#pragma unroll
  for (int j = 0; j < 2; ++j)
#pragma unroll
    for (int kap = 0; kap < 2; ++kap)
#pragma unroll
      for (int qb = 0; qb < 2; ++qb) {
        u32x4 uw;
        uw[0] = uB[qb][4 * kap + 0]; uw[1] = uB[qb][4 * kap + 1];
        uw[2] = uB[qb][4 * kap + 2]; uw[3] = uB[qb][4 * kap + 3];
        bf16x8 pa = __builtin_bit_cast(bf16x8, uw);
        o[qb][j] = __builtin_amdgcn_mfma_f32_32x32x16_bf16(pa, vB[2 * j + kap], o[qb][j], 0, 0, 0);
      }

  // ls: cross-h reduce, publish per-wave to LDS
  ls[0] += __shfl_xor(ls[0], 32);
  ls[1] += __shfl_xor(ls[1], 32);
  if (h == 0) { lsh[w][0][q5] = ls[0]; lsh[w][1][q5] = ls[1]; }

  // cross-wave O combine: each wave publishes its partner-block partial via Ks (16 KB)
  float* osh = (float*)Ks;  // [2 waves][2 qb][64 lanes][16]
#pragma unroll
  for (int qb = 0; qb < 2; ++qb)
    *(f32x16*)(osh + ((w * 2 + qb) * 64 + lane) * 16) = o[qb][1];
  __syncthreads();

#pragma unroll
  for (int qb = 0; qb < 2; ++qb) {
    float lt = ls[qb] + lsh[1 - w][qb][q5];
    float iv = __builtin_amdgcn_rcpf(lt);
    f32x16 p = *(const f32x16*)(osh + (((1 - w) * 2 + qb) * 64 + lane) * 16);
#pragma unroll
    for (int g4 = 0; g4 < 4; ++g4)
#pragma unroll
      for (int r = 0; r < 4; ++r) {
        int qr = g4 * 8 + 4 * h + r;
        float il = __shfl(iv, qr);
        size_t row = (size_t)b * 2048 + qt * 64 + qb * 32 + qr;
        Oa[row * 1024 + hd * 64 + w * 32 + q5] = (bf16)((o[qb][0][g4 * 4 + r] + p[g4 * 4 + r]) * il);
      }
  }
}

extern "C" void kernel_launch(void* const* d_in, const int* in_sizes, int n_in,
                              void* d_out, int out_size, void* d_ws, size_t ws_size,
                              hipStream_t stream) {
  (void)in_sizes; (void)n_in; (void)out_size; (void)ws_size;
  const float* x  = (const float*)d_in[0];
  const float* y  = (const float*)d_in[1];
  const float* Wq = (const float*)d_in[2];
  const float* bq = (const float*)d_in[3];
  const float* Wk = (const float*)d_in[4];
  const float* bk = (const float*)d_in[5];
  const float* Wv = (const float*)d_in[6];
  const float* bv = (const float*)d_in[7];
  const float* Wo = (const float*)d_in[8];
  const float* bo = (const float*)d_in[9];

  char* ws = (char*)d_ws;
  bf16* xb  = (bf16*)(ws + 0);
  bf16* yb  = (bf16*)(ws + 8388608);
  bf16* Qb  = (bf16*)(ws + 16777216);
  bf16* Kb  = (bf16*)(ws + 25165824);
  bf16* Vtb = (bf16*)(ws + 33554432);
  bf16* Oab = (bf16*)(ws + 41943040);
  bf16* Wqt = (bf16*)(ws + 50331648);
  bf16* Wkt = (bf16*)(ws + 52428800);
  bf16* Wvt = (bf16*)(ws + 54525952);
  bf16* Wot = (bf16*)(ws + 56623104);

  cvtw_kernel<<<12288, 256, 0, stream>>>(x, y, xb, yb, Wq, Wk, Wv, Wo, Wqt, Wkt, Wvt, Wot);
  gemm_qkv<<<dim3(32, 8, 3), 256, 0, stream>>>(xb, yb, Wqt, Wkt, Wvt, bq, bk, bv, Qb, Kb, Vtb);
  attn_kernel<<<dim3(32, 32), dim3(128), 0, stream>>>(Qb, Kb, Vtb, Oab);
  gemm_out<<<dim3(32, 16), 256, 0, stream>>>(Oab, Wot, bo, (float*)d_out);
}

// Round 8
// 117.905 us; speedup vs baseline: 1.4620x; 1.0953x over previous
//
#include <hip/hip_runtime.h>
#include <hip/hip_bf16.h>

typedef __bf16 bf16;
typedef __attribute__((ext_vector_type(8))) __bf16 bf16x8;
typedef __attribute__((ext_vector_type(4))) __bf16 bf16x4;
typedef __attribute__((ext_vector_type(4))) float f32x4;
typedef __attribute__((ext_vector_type(16))) float f32x16;
typedef __attribute__((ext_vector_type(4))) unsigned int u32x4;

__device__ __forceinline__ void gload_lds16(const void* g, void* l) {
  __builtin_amdgcn_global_load_lds((const __attribute__((address_space(1))) void*)g,
                                   (__attribute__((address_space(3))) void*)l, 16, 0, 0);
}

__device__ __forceinline__ float exp2_fast(float x) {
  float r;
  asm("v_exp_f32 %0, %1" : "=v"(r) : "v"(x));
  return r;
}

__device__ __forceinline__ unsigned cvtpk(float lo, float hi) {
  unsigned r;
  asm("v_cvt_pk_bf16_f32 %0, %1, %2" : "=v"(r) : "v"(lo), "v"(hi));
  return r;
}

__device__ __forceinline__ void plswap(unsigned& a, unsigned& b) {
  asm("v_permlane32_swap_b32 %0, %1" : "+v"(a), "+v"(b));
}

// ---------------- merged f32->bf16 convert (x,y) + weight transpose-convert ----------------
__global__ __launch_bounds__(256) void cvtw_kernel(
    const float* __restrict__ x, const float* __restrict__ y,
    bf16* __restrict__ xb, bf16* __restrict__ yb,
    const float* __restrict__ W0, const float* __restrict__ W1,
    const float* __restrict__ W2, const float* __restrict__ W3,
    bf16* __restrict__ T0, bf16* __restrict__ T1,
    bf16* __restrict__ T2, bf16* __restrict__ T3) {
  __shared__ float t[32][33];
  const int bid = blockIdx.x, tid = threadIdx.x;
  if (bid < 4096) {
    const int z = bid >> 10, rem = bid & 1023;
    const int bx = rem & 31, by = rem >> 5;
    const float* W; bf16* T;
    switch (z) {
      case 0: W = W0; T = T0; break;
      case 1: W = W1; T = T1; break;
      case 2: W = W2; T = T2; break;
      default: W = W3; T = T3; break;
    }
    const int tx = tid & 31, ty = tid >> 5;
    const int bn = bx * 32, bk = by * 32;
#pragma unroll
    for (int i = 0; i < 32; i += 8)
      t[ty + i][tx] = W[(size_t)(bk + ty + i) * 1024 + bn + tx];
    __syncthreads();
#pragma unroll
    for (int i = 0; i < 32; i += 8)
      T[(size_t)(bn + ty + i) * 1024 + bk + tx] = (bf16)t[tx][ty + i];
  } else {
    const int n4 = 1048576;
    int i = (bid - 4096) * 256 + tid;
    const float4* in = (const float4*)x; bf16x4* out = (bf16x4*)xb;
    if (i >= n4) { in = (const float4*)y; out = (bf16x4*)yb; i -= n4; }
    float4 v = in[i];
    bf16x4 o;
    o[0] = (bf16)v.x; o[1] = (bf16)v.y; o[2] = (bf16)v.z; o[3] = (bf16)v.w;
    out[i] = o;
  }
}

// ---------------- merged Q/K/V projection GEMM, 128x128 tile, 8 waves, double-buffered --------
// z=0: Q = (xb*Wqt+bq)*QSCALE (bf16, prescaled by log2e/sqrt(2048)); z=1: K; z=2: V transposed.
// 512 threads = 8 waves (2 row x 4 col), wave tile 64x32. 768 blocks -> 3/CU, 24 waves/CU.
__global__ __launch_bounds__(512, 6) void gemm_qkv(
    const bf16* __restrict__ xb, const bf16* __restrict__ yb,
    const bf16* __restrict__ Wqt, const bf16* __restrict__ Wkt, const bf16* __restrict__ Wvt,
    const float* __restrict__ bq, const float* __restrict__ bk, const float* __restrict__ bv,
    bf16* __restrict__ Qb, bf16* __restrict__ Kb, bf16* __restrict__ Vtb) {
  constexpr int K = 1024;
  constexpr float QSCALE = (float)(1.4426950408889634 / 45.254833995939045);
  __shared__ bf16 As[2][128 * 32];
  __shared__ bf16 Bs[2][128 * 32];
  const int z = blockIdx.z;
  const bf16* A  = (z == 0) ? xb : yb;
  const bf16* Bt = (z == 0) ? Wqt : (z == 1) ? Wkt : Wvt;
  const float* bias = (z == 0) ? bq : (z == 1) ? bk : bv;

  const int tid = threadIdx.x;
  const int wave = tid >> 6, lane = tid & 63;
  const int g = lane >> 4, r15 = lane & 15;
  const int m0 = blockIdx.x * 128, n0 = blockIdx.y * 128;
  const int wr = wave >> 2, wc = wave & 3;  // 2x4 wave grid, wave tile 64x32

  f32x4 acc[4][2] = {};

  const int rowA = tid >> 2, chA = tid & 3;  // 512 threads -> one 16B chunk each

  auto stage = [&](int buf, int k0) {
    gload_lds16(A  + (size_t)(m0 + rowA) * K + k0 + chA * 8, (char*)As[buf] + tid * 16);
    gload_lds16(Bt + (size_t)(n0 + rowA) * K + k0 + chA * 8, (char*)Bs[buf] + tid * 16);
  };

  stage(0, 0);
  __syncthreads();
  int cur = 0;
  for (int t = 0; t < K / 32; ++t) {
    if (t + 1 < K / 32) stage(cur ^ 1, (t + 1) * 32);
    bf16x8 af[4], bfr[2];
#pragma unroll
    for (int mi = 0; mi < 4; ++mi)
      af[mi] = *(const bf16x8*)((const char*)As[cur] + ((wr * 64 + mi * 16 + r15) * 64 + g * 16));
#pragma unroll
    for (int nj = 0; nj < 2; ++nj)
      bfr[nj] = *(const bf16x8*)((const char*)Bs[cur] + ((wc * 32 + nj * 16 + r15) * 64 + g * 16));
#pragma unroll
    for (int mi = 0; mi < 4; ++mi)
#pragma unroll
      for (int nj = 0; nj < 2; ++nj)
        acc[mi][nj] = __builtin_amdgcn_mfma_f32_16x16x32_bf16(af[mi], bfr[nj], acc[mi][nj], 0, 0, 0);
    __syncthreads();
    cur ^= 1;
  }

  const float scl = (z == 0) ? QSCALE : 1.0f;
#pragma unroll
  for (int mi = 0; mi < 4; ++mi) {
#pragma unroll
    for (int nj = 0; nj < 2; ++nj) {
      int row = m0 + wr * 64 + mi * 16 + g * 4;
      int col = n0 + wc * 32 + nj * 16 + r15;
      float bv_ = bias[col];
      if (z < 2) {
        bf16* C = (z == 0) ? Qb : Kb;
#pragma unroll
        for (int r = 0; r < 4; ++r)
          C[(size_t)(row + r) * 1024 + col] = (bf16)((acc[mi][nj][r] + bv_) * scl);
      } else {
        int b = row >> 11, n = row & 2047;
        bf16x4 pkv;
#pragma unroll
        for (int r = 0; r < 4; ++r)
          pkv[r] = (bf16)(acc[mi][nj][r] + bv_);
        *(bf16x4*)(Vtb + ((size_t)b * 1024 + col) * 2048 + n) = pkv;
      }
    }
  }
}

// ---------------- out-projection GEMM, 128x64 tile, 8 waves, bias+ReLU, f32 out ----------------
// 512 threads = 8 waves (4 row x 2 col), wave tile 32x32. 512 blocks -> 2/CU, 16 waves/CU.
__global__ __launch_bounds__(512, 4) void gemm_out(
    const bf16* __restrict__ A, const bf16* __restrict__ Bt,
    const float* __restrict__ bias, float* __restrict__ C) {
  constexpr int K = 1024;
  __shared__ bf16 As[2][128 * 32];
  __shared__ bf16 Bs[2][64 * 32];
  const int tid = threadIdx.x;
  const int wave = tid >> 6, lane = tid & 63;
  const int g = lane >> 4, r15 = lane & 15;
  const int m0 = blockIdx.x * 128, n0 = blockIdx.y * 64;
  const int wr = wave >> 1, wc = wave & 1;  // 4x2 wave grid, wave tile 32x32

  f32x4 acc[2][2] = {};

  const int rowA = tid >> 2, chA = tid & 3;

  auto stage = [&](int buf, int k0) {
    gload_lds16(A + (size_t)(m0 + rowA) * K + k0 + chA * 8, (char*)As[buf] + tid * 16);
    if (tid < 256)
      gload_lds16(Bt + (size_t)(n0 + rowA) * K + k0 + chA * 8, (char*)Bs[buf] + tid * 16);
  };

  stage(0, 0);
  __syncthreads();
  int cur = 0;
  for (int t = 0; t < K / 32; ++t) {
    if (t + 1 < K / 32) stage(cur ^ 1, (t + 1) * 32);
    bf16x8 af[2], bfr[2];
#pragma unroll
    for (int mi = 0; mi < 2; ++mi)
      af[mi] = *(const bf16x8*)((const char*)As[cur] + ((wr * 32 + mi * 16 + r15) * 64 + g * 16));
#pragma unroll
    for (int nj = 0; nj < 2; ++nj)
      bfr[nj] = *(const bf16x8*)((const char*)Bs[cur] + ((wc * 32 + nj * 16 + r15) * 64 + g * 16));
#pragma unroll
    for (int mi = 0; mi < 2; ++mi)
#pragma unroll
      for (int nj = 0; nj < 2; ++nj)
        acc[mi][nj] = __builtin_amdgcn_mfma_f32_16x16x32_bf16(af[mi], bfr[nj], acc[mi][nj], 0, 0, 0);
    __syncthreads();
    cur ^= 1;
  }

#pragma unroll
  for (int mi = 0; mi < 2; ++mi)
#pragma unroll
    for (int nj = 0; nj < 2; ++nj) {
      int row = m0 + wr * 32 + mi * 16 + g * 4;
      int col = n0 + wc * 32 + nj * 16 + r15;
      float bv_ = bias[col];
#pragma unroll
      for (int r = 0; r < 4; ++r)
        C[(size_t)(row + r) * 1024 + col] = fmaxf(acc[mi][nj][r] + bv_, 0.0f);
    }
}

// ---------------- flash attention v5 (verbatim from R5, passing): kv-split waves + att[2] ------
// Q prescaled by log2e/sqrt(2048). Q,K: [B][2048][1024] bf16. V^T: [B][1024][2048] bf16.
// Block: 128 threads = 2 waves; 64 q-rows/block; wave w owns kv rows [32w,32w+32) of each tile.
__global__ __launch_bounds__(128, 2) void attn_kernel(
    const bf16* __restrict__ Q, const bf16* __restrict__ Kin,
    const bf16* __restrict__ Vt, bf16* __restrict__ Oa) {
  __shared__ bf16 Ks[2][64 * 64];
  __shared__ bf16 Vs[2][64 * 64];
  __shared__ float lsh[2][2][32];
  const int tid = threadIdx.x;
  const int w = tid >> 6, lane = tid & 63;
  const int q5 = lane & 31, h = lane >> 5;

  int i = blockIdx.y * 32 + blockIdx.x;
  int xcd = i & 7, slot = i >> 3;
  int bh = xcd * 4 + (slot >> 5), qt = slot & 31;
  int b = bh >> 4, hd = bh & 15;

  const bf16* Qg = Q + ((size_t)b * 2048 + qt * 64) * 1024 + hd * 64;
  const bf16* Kg = Kin + (size_t)b * 2048 * 1024 + hd * 64;
  const bf16* Vg = Vt + ((size_t)b * 1024 + hd * 64) * 2048;

  bf16x8 qf[2][4];
#pragma unroll
  for (int qb = 0; qb < 2; ++qb)
#pragma unroll
    for (int ks = 0; ks < 4; ++ks)
      qf[qb][ks] = *(const bf16x8*)(Qg + (size_t)(qb * 32 + q5) * 1024 + ks * 16 + h * 8);

  f32x16 o[2][2] = {};
  float ls[2] = {};

  auto stage = [&](int buf, int kv0) {
#pragma unroll
    for (int ii = 0; ii < 4; ++ii) {
      int c = tid + ii * 128;
      int row = c >> 3;
      int sl = (c & 7) ^ (row & 7) ^ ((row >> 3) & 1);
      gload_lds16(Kg + (size_t)(kv0 + row) * 1024 + sl * 8, (char*)Ks[buf] + c * 16);
      gload_lds16(Vg + (size_t)row * 2048 + kv0 + sl * 8, (char*)Vs[buf] + c * 16);
    }
  };

  stage(0, 0);
  __syncthreads();
  int cur = 0;

  const int krow = w * 32 + q5;
  const int kswz = (krow & 7) ^ ((krow >> 3) & 1);

  unsigned uA[2][8], uB[2][8];
  bf16x8 vA[4], vB[4];

  auto phase = [&](int t, unsigned (&uin)[2][8], unsigned (&uout)[2][8],
                   bf16x8 (&vin)[4], bf16x8 (&vout)[4], bool doStage, bool doPV) {
    if (doStage) stage(cur ^ 1, (t + 1) * 64);

    f32x16 s[2] = {};
    __builtin_amdgcn_s_setprio(1);
#pragma unroll
    for (int ks = 0; ks < 4; ++ks) {
      bf16x8 kf = *(const bf16x8*)((const char*)Ks[cur] + krow * 128 + (((2 * ks + h) ^ kswz) << 4));
      s[0] = __builtin_amdgcn_mfma_f32_32x32x16_bf16(kf, qf[0][ks], s[0], 0, 0, 0);
      s[1] = __builtin_amdgcn_mfma_f32_32x32x16_bf16(kf, qf[1][ks], s[1], 0, 0, 0);
    }

#pragma unroll
    for (int j = 0; j < 2; ++j) {
      const int db = w ^ j;
      const int vrow0 = db * 32 + q5;
      const int vswz = (vrow0 & 7) ^ ((vrow0 >> 3) & 1);
#pragma unroll
      for (int kap = 0; kap < 2; ++kap)
        vout[2 * j + kap] = *(const bf16x8*)((const char*)Vs[cur] + vrow0 * 128 +
                                             (((4 * w + 2 * kap + h) ^ vswz) << 4));
    }

    if (doPV) {
#pragma unroll
      for (int j = 0; j < 2; ++j)
#pragma unroll
        for (int kap = 0; kap < 2; ++kap)
#pragma unroll
          for (int qb = 0; qb < 2; ++qb) {
            u32x4 uw;
            uw[0] = uin[qb][4 * kap + 0]; uw[1] = uin[qb][4 * kap + 1];
            uw[2] = uin[qb][4 * kap + 2]; uw[3] = uin[qb][4 * kap + 3];
            bf16x8 pa = __builtin_bit_cast(bf16x8, uw);
            o[qb][j] = __builtin_amdgcn_mfma_f32_32x32x16_bf16(pa, vin[2 * j + kap], o[qb][j], 0, 0, 0);
          }
    }
    __builtin_amdgcn_s_setprio(0);

#pragma unroll
    for (int qb = 0; qb < 2; ++qb) {
      float e[16];
#pragma unroll
      for (int jj = 0; jj < 16; ++jj) e[jj] = exp2_fast(s[qb][jj]);
      ls[qb] += ((((e[0] + e[1]) + (e[2] + e[3])) + ((e[4] + e[5]) + (e[6] + e[7]))) +
                 (((e[8] + e[9]) + (e[10] + e[11])) + ((e[12] + e[13]) + (e[14] + e[15]))));
#pragma unroll
      for (int p = 0; p < 8; ++p) uout[qb][p] = cvtpk(e[2 * p], e[2 * p + 1]);
      plswap(uout[qb][0], uout[qb][2]); plswap(uout[qb][1], uout[qb][3]);
      plswap(uout[qb][4], uout[qb][6]); plswap(uout[qb][5], uout[qb][7]);
    }

    __syncthreads();
    cur ^= 1;
  };

  phase(0, uB, uA, vB, vA, true, false);
  for (int t = 1; t < 31; t += 2) {
    phase(t, uA, uB, vA, vB, true, true);
    phase(t + 1, uB, uA, vB, vA, true, true);
  }
  phase(31, uA, uB, vA, vB, false, true);
#pragma unroll
  for (int j = 0; j < 2; ++j)
#pragma unroll
    for (int kap = 0; kap < 2; ++kap)
#pragma unroll
      for (int qb = 0; qb < 2; ++qb) {
        u32x4 uw;
        uw[0] = uB[qb][4 * kap + 0]; uw[1] = uB[qb][4 * kap + 1];
        uw[2] = uB[qb][4 * kap + 2]; uw[3] = uB[qb][4 * kap + 3];
        bf16x8 pa = __builtin_bit_cast(bf16x8, uw);
        o[qb][j] = __builtin_amdgcn_mfma_f32_32x32x16_bf16(pa, vB[2 * j + kap], o[qb][j], 0, 0, 0);
      }

  ls[0] += __shfl_xor(ls[0], 32);
  ls[1] += __shfl_xor(ls[1], 32);
  if (h == 0) { lsh[w][0][q5] = ls[0]; lsh[w][1][q5] = ls[1]; }

  float* osh = (float*)Ks;
#pragma unroll
  for (int qb = 0; qb < 2; ++qb)
    *(f32x16*)(osh + ((w * 2 + qb) * 64 + lane) * 16) = o[qb][1];
  __syncthreads();

#pragma unroll
  for (int qb = 0; qb < 2; ++qb) {
    float lt = ls[qb] + lsh[1 - w][qb][q5];
    float iv = __builtin_amdgcn_rcpf(lt);
    f32x16 p = *(const f32x16*)(osh + (((1 - w) * 2 + qb) * 64 + lane) * 16);
#pragma unroll
    for (int g4 = 0; g4 < 4; ++g4)
#pragma unroll
      for (int r = 0; r < 4; ++r) {
        int qr = g4 * 8 + 4 * h + r;
        float il = __shfl(iv, qr);
        size_t row = (size_t)b * 2048 + qt * 64 + qb * 32 + qr;
        Oa[row * 1024 + hd * 64 + w * 32 + q5] = (bf16)((o[qb][0][g4 * 4 + r] + p[g4 * 4 + r]) * il);
      }
  }
}

extern "C" void kernel_launch(void* const* d_in, const int* in_sizes, int n_in,
                              void* d_out, int out_size, void* d_ws, size_t ws_size,
                              hipStream_t stream) {
  (void)in_sizes; (void)n_in; (void)out_size; (void)ws_size;
  const float* x  = (const float*)d_in[0];
  const float* y  = (const float*)d_in[1];
  const float* Wq = (const float*)d_in[2];
  const float* bq = (const float*)d_in[3];
  const float* Wk = (const float*)d_in[4];
  const float* bk = (const float*)d_in[5];
  const float* Wv = (const float*)d_in[6];
  const float* bv = (const float*)d_in[7];
  const float* Wo = (const float*)d_in[8];
  const float* bo = (const float*)d_in[9];

  char* ws = (char*)d_ws;
  bf16* xb  = (bf16*)(ws + 0);
  bf16* yb  = (bf16*)(ws + 8388608);
  bf16* Qb  = (bf16*)(ws + 16777216);
  bf16* Kb  = (bf16*)(ws + 25165824);
  bf16* Vtb = (bf16*)(ws + 33554432);
  bf16* Oab = (bf16*)(ws + 41943040);
  bf16* Wqt = (bf16*)(ws + 50331648);
  bf16* Wkt = (bf16*)(ws + 52428800);
  bf16* Wvt = (bf16*)(ws + 54525952);
  bf16* Wot = (bf16*)(ws + 56623104);

  cvtw_kernel<<<12288, 256, 0, stream>>>(x, y, xb, yb, Wq, Wk, Wv, Wo, Wqt, Wkt, Wvt, Wot);
  gemm_qkv<<<dim3(32, 8, 3), 512, 0, stream>>>(xb, yb, Wqt, Wkt, Wvt, bq, bk, bv, Qb, Kb, Vtb);
  attn_kernel<<<dim3(32, 32), dim3(128), 0, stream>>>(Qb, Kb, Vtb, Oab);
  gemm_out<<<dim3(32, 16), 512, 0, stream>>>(Oab, Wot, bo, (float*)d_out);
}